// Round 1
// baseline (4237.096 us; speedup 1.0000x reference)
//
#include <hip/hip_runtime.h>
#include <hip/hip_bf16.h>

// ---------------------------------------------------------------------------
// GraphSAGE 2-layer: h = relu(mean_agg(x) @ W1l^T + b1 + x @ W1r^T)
//                    out = mean_agg(h) @ W2l^T + b2 + h @ W2r^T
// N=50000, E=800000, C: 128 -> 256 -> 2, fp32.
// Round 1: correctness-first. Atomic scatter aggregation + tiled fp32 GEMM.
// ---------------------------------------------------------------------------

#define IN_C 128
#define HID_C 256

// Build wt[k][o] = (k<128 ? W1l[o][k] : W1r[o][k-128]); k-major 256x256 so the
// GEMM's B-tile loads are coalesced.
__global__ void transpose_w1(const float* __restrict__ w1l,
                             const float* __restrict__ w1r,
                             float* __restrict__ wt) {
    int idx = blockIdx.x * 256 + threadIdx.x;   // 65536 total
    int k = idx >> 8, o = idx & 255;
    wt[idx] = (k < IN_C) ? w1l[o * IN_C + k] : w1r[o * IN_C + (k - IN_C)];
}

// Layer-1 scatter: one thread per (edge, 4-feature group). 32 consecutive
// threads read one full source row (coalesced float4), atomically add into
// agg[dst]. g==0 lane also bumps the degree counter (graph reused by layer 2).
__global__ void scatter1(const int* __restrict__ ei, const float* __restrict__ x,
                         float* __restrict__ agg, float* __restrict__ cnt, int E_) {
    int t = blockIdx.x * 256 + threadIdx.x;
    int e = t >> 5, g = t & 31;
    if (e >= E_) return;
    int src = ei[e];
    int dst = ei[E_ + e];
    float4 v = *(const float4*)&x[src * IN_C + g * 4];
    float* a = &agg[dst * IN_C + g * 4];
    unsafeAtomicAdd(a + 0, v.x);
    unsafeAtomicAdd(a + 1, v.y);
    unsafeAtomicAdd(a + 2, v.z);
    unsafeAtomicAdd(a + 3, v.w);
    if (g == 0) unsafeAtomicAdd(&cnt[dst], 1.0f);
}

// Layer-2 scatter: one thread per (edge, 4-feature group of 256).
__global__ void scatter2(const int* __restrict__ ei, const float* __restrict__ h,
                         float* __restrict__ agg, int E_) {
    int t = blockIdx.x * 256 + threadIdx.x;
    int e = t >> 6, g = t & 63;
    if (e >= E_) return;
    int src = ei[e];
    int dst = ei[E_ + e];
    float4 v = *(const float4*)&h[src * HID_C + g * 4];
    float* a = &agg[dst * HID_C + g * 4];
    unsafeAtomicAdd(a + 0, v.x);
    unsafeAtomicAdd(a + 1, v.y);
    unsafeAtomicAdd(a + 2, v.z);
    unsafeAtomicAdd(a + 3, v.w);
}

// GEMM1: h[N,256] = relu(A @ wt + b1), A = [agg1*inv | x] (N x 256 combined K).
// 64x64 tile per block, BK=16, 256 threads, 4x4 micro-tile per thread.
#define BM 64
#define BN 64
#define BK 16
#define LDP (BM + 4)   // padded LDS stride (multiple of 4 -> float4-aligned)

__global__ __launch_bounds__(256) void gemm1(
    const float* __restrict__ x, const float* __restrict__ agg,
    const float* __restrict__ cnt, const float* __restrict__ wt,
    const float* __restrict__ b1, float* __restrict__ h, int n_nodes) {
    __shared__ float As[BK][LDP];
    __shared__ float Bs[BK][LDP];

    const int tid = threadIdx.x;
    const int row0 = blockIdx.x * BM;
    const int col0 = blockIdx.y * BN;

    const int tx = tid & 15;   // micro col group
    const int ty = tid >> 4;   // micro row group
    float acc[4][4] = {};

    // A-tile load mapping: 4 threads per row (k-chunks), rows consecutive.
    const int lrow = tid >> 2;
    const int lk4 = (tid & 3) * 4;
    // B-tile load mapping: 16 threads per k-row, coalesced along o.
    const int bk = tid >> 4;
    const int bn4 = (tid & 15) * 4;

    int arow = row0 + lrow;
    if (arow >= n_nodes) arow = n_nodes - 1;
    const float inv = 1.0f / fmaxf(cnt[arow], 1.0f);

    for (int k0 = 0; k0 < 2 * IN_C; k0 += BK) {
        float4 av;
        if (k0 < IN_C) {
            av = *(const float4*)&agg[arow * IN_C + k0 + lk4];
            av.x *= inv; av.y *= inv; av.z *= inv; av.w *= inv;
        } else {
            av = *(const float4*)&x[arow * IN_C + (k0 - IN_C) + lk4];
        }
        float4 bv = *(const float4*)&wt[(k0 + bk) * HID_C + col0 + bn4];

        __syncthreads();   // previous iter's LDS reads done
        As[lk4 + 0][lrow] = av.x;
        As[lk4 + 1][lrow] = av.y;
        As[lk4 + 2][lrow] = av.z;
        As[lk4 + 3][lrow] = av.w;
        *(float4*)&Bs[bk][bn4] = bv;
        __syncthreads();

#pragma unroll
        for (int k = 0; k < BK; ++k) {
            float4 a4 = *(const float4*)&As[k][ty * 4];
            float4 b4 = *(const float4*)&Bs[k][tx * 4];
            float ar[4] = {a4.x, a4.y, a4.z, a4.w};
            float br[4] = {b4.x, b4.y, b4.z, b4.w};
#pragma unroll
            for (int i = 0; i < 4; ++i)
#pragma unroll
                for (int j = 0; j < 4; ++j) acc[i][j] = fmaf(ar[i], br[j], acc[i][j]);
        }
    }

    const float4 bias = *(const float4*)&b1[col0 + tx * 4];
#pragma unroll
    for (int i = 0; i < 4; ++i) {
        int r = row0 + ty * 4 + i;
        if (r < n_nodes) {
            float4 o;
            o.x = fmaxf(acc[i][0] + bias.x, 0.0f);
            o.y = fmaxf(acc[i][1] + bias.y, 0.0f);
            o.z = fmaxf(acc[i][2] + bias.z, 0.0f);
            o.w = fmaxf(acc[i][3] + bias.w, 0.0f);
            *(float4*)&h[r * HID_C + col0 + tx * 4] = o;
        }
    }
}

// GEMM2: out[i][0..1] = sum_k agg2[i][k]*inv*W2l[o][k] + h[i][k]*W2r[o][k] + b2.
// One wave per node, 4 k-elements per lane, shuffle reduction.
__global__ __launch_bounds__(256) void gemm2(
    const float* __restrict__ h, const float* __restrict__ agg,
    const float* __restrict__ cnt, const float* __restrict__ w2l,
    const float* __restrict__ b2, const float* __restrict__ w2r,
    float* __restrict__ out, int n_nodes) {
    int wave = threadIdx.x >> 6;
    int lane = threadIdx.x & 63;
    int i = blockIdx.x * 4 + wave;
    if (i >= n_nodes) return;
    float inv = 1.0f / fmaxf(cnt[i], 1.0f);
    float4 a4 = *(const float4*)&agg[i * HID_C + lane * 4];
    float4 h4 = *(const float4*)&h[i * HID_C + lane * 4];
    float4 l0 = *(const float4*)&w2l[0 * HID_C + lane * 4];
    float4 l1 = *(const float4*)&w2l[1 * HID_C + lane * 4];
    float4 r0 = *(const float4*)&w2r[0 * HID_C + lane * 4];
    float4 r1 = *(const float4*)&w2r[1 * HID_C + lane * 4];
    a4.x *= inv; a4.y *= inv; a4.z *= inv; a4.w *= inv;
    float s0 = a4.x * l0.x + a4.y * l0.y + a4.z * l0.z + a4.w * l0.w
             + h4.x * r0.x + h4.y * r0.y + h4.z * r0.z + h4.w * r0.w;
    float s1 = a4.x * l1.x + a4.y * l1.y + a4.z * l1.z + a4.w * l1.w
             + h4.x * r1.x + h4.y * r1.y + h4.z * r1.z + h4.w * r1.w;
#pragma unroll
    for (int off = 32; off > 0; off >>= 1) {
        s0 += __shfl_down(s0, off);
        s1 += __shfl_down(s1, off);
    }
    if (lane == 0) {
        out[i * 2 + 0] = s0 + b2[0];
        out[i * 2 + 1] = s1 + b2[1];
    }
}

extern "C" void kernel_launch(void* const* d_in, const int* in_sizes, int n_in,
                              void* d_out, int out_size, void* d_ws, size_t ws_size,
                              hipStream_t stream) {
    const float* x   = (const float*)d_in[0];
    const int*   ei  = (const int*)d_in[1];
    const float* W1l = (const float*)d_in[2];
    const float* b1  = (const float*)d_in[3];
    const float* W1r = (const float*)d_in[4];
    const float* W2l = (const float*)d_in[5];
    const float* b2  = (const float*)d_in[6];
    const float* W2r = (const float*)d_in[7];
    float* out = (float*)d_out;
    float* ws  = (float*)d_ws;

    const int N_ = in_sizes[0] / IN_C;      // 50000
    const int E_ = in_sizes[1] / 2;         // 800000

    // Workspace layout (floats). agg region reused: layer1 [N,128], layer2 [N,256].
    float* agg = ws;                                    // 12,800,000 floats
    float* cnt = ws + (size_t)N_ * HID_C;               //     50,000
    float* h   = cnt + 50176;                           // 12,800,000 (16B aligned)
    float* wt1 = h + (size_t)N_ * HID_C;                //     65,536
    // total ~102.9 MB

    // ---- Layer 1 ----
    hipMemsetAsync(agg, 0, (size_t)N_ * IN_C * sizeof(float), stream);
    hipMemsetAsync(cnt, 0, (size_t)N_ * sizeof(float), stream);
    transpose_w1<<<256, 256, 0, stream>>>(W1l, W1r, wt1);
    scatter1<<<(E_ * 32 + 255) / 256, 256, 0, stream>>>(ei, x, agg, cnt, E_);
    gemm1<<<dim3((N_ + BM - 1) / BM, HID_C / BN), 256, 0, stream>>>(
        x, agg, cnt, wt1, b1, h, N_);

    // ---- Layer 2 ----
    hipMemsetAsync(agg, 0, (size_t)N_ * HID_C * sizeof(float), stream);
    scatter2<<<(E_ * 64 + 255) / 256, 256, 0, stream>>>(ei, h, agg, E_);
    gemm2<<<(N_ + 3) / 4, 256, 0, stream>>>(h, agg, cnt, W2l, b2, W2r, out, N_);
}

// Round 2
// 501.387 us; speedup vs baseline: 8.4507x; 8.4507x over previous
//
#include <hip/hip_runtime.h>
#include <hip/hip_bf16.h>

// ---------------------------------------------------------------------------
// GraphSAGE 2-layer: h = relu(mean_agg(x) @ W1l^T + b1 + x @ W1r^T)
//                    out = mean_agg(h) @ W2l^T + b2 + h @ W2r^T
// N=50000, E=800000, C: 128 -> 256 -> 2, fp32.
// Round 2: kill atomic scatter traffic.
//  - Layer 1 aggregation: CSR (dst-sorted) gather, one wave per node.
//  - Layer 2: commute linear with mean -> project h to 2 dims FIRST, then
//    scatter-add only 2 floats/edge into an L2-resident N*2 buffer.
// ---------------------------------------------------------------------------

#define IN_C 128
#define HID_C 256

// ---- CSR build -------------------------------------------------------------

__global__ void hist_dst(const int* __restrict__ ei, int* __restrict__ deg, int E_) {
    int e = blockIdx.x * 256 + threadIdx.x;
    if (e >= E_) return;
    atomicAdd(&deg[ei[E_ + e]], 1);
}

// Single-block exclusive scan over deg[0..n) -> rowptr[0..n], cursor copy.
// 1024 threads, wave-level shfl scan + cross-wave LDS scan, serial carry.
__global__ __launch_bounds__(1024) void scan_deg(const int* __restrict__ deg,
                                                 int* __restrict__ rowptr,
                                                 int* __restrict__ cursor, int n) {
    __shared__ int wsum[16];
    __shared__ int carry_s;
    const int lane = threadIdx.x & 63;
    const int wid = threadIdx.x >> 6;
    if (threadIdx.x == 0) carry_s = 0;
    __syncthreads();
    for (int base = 0; base < n; base += 1024) {
        int i = base + threadIdx.x;
        int v = (i < n) ? deg[i] : 0;
        int incl = v;
#pragma unroll
        for (int off = 1; off < 64; off <<= 1) {
            int t = __shfl_up(incl, off);
            if (lane >= off) incl += t;
        }
        if (lane == 63) wsum[wid] = incl;
        __syncthreads();
        int woff = 0;
        for (int w = 0; w < 16; ++w)
            if (w < wid) woff += wsum[w];
        int excl = carry_s + woff + incl - v;
        if (i < n) { rowptr[i] = excl; cursor[i] = excl; }
        __syncthreads();
        if (threadIdx.x == 1023) carry_s += woff + incl;  // full chunk sum
        __syncthreads();
    }
    if (threadIdx.x == 0) rowptr[n] = carry_s;
}

__global__ void fill_csr(const int* __restrict__ ei, int* __restrict__ cursor,
                         int* __restrict__ elist, int E_) {
    int e = blockIdx.x * 256 + threadIdx.x;
    if (e >= E_) return;
    int dst = ei[E_ + e];
    int pos = atomicAdd(&cursor[dst], 1);
    elist[pos] = ei[e];   // store src
}

// ---- Layer 1 ---------------------------------------------------------------

// One wave per node: accumulate neighbors' x rows (float2/lane = 128 feats),
// write the mean once. x (25.6 MB) is L3-resident -> gather reads are cached.
__global__ __launch_bounds__(256) void gather_agg1(
    const int* __restrict__ rowptr, const int* __restrict__ elist,
    const float* __restrict__ x, float* __restrict__ agg, int n) {
    int node = blockIdx.x * 4 + (threadIdx.x >> 6);
    int lane = threadIdx.x & 63;
    if (node >= n) return;
    int beg = rowptr[node], end = rowptr[node + 1];
    float sx = 0.0f, sy = 0.0f;
    for (int e = beg; e < end; ++e) {
        int src = elist[e];
        float2 v = *(const float2*)&x[src * IN_C + lane * 2];
        sx += v.x; sy += v.y;
    }
    float inv = 1.0f / (float)max(end - beg, 1);
    float2 o = {sx * inv, sy * inv};
    *(float2*)&agg[node * IN_C + lane * 2] = o;
}

// Build wt[k][o] = (k<128 ? W1l[o][k] : W1r[o][k-128]); k-major 256x256.
__global__ void transpose_w1(const float* __restrict__ w1l,
                             const float* __restrict__ w1r,
                             float* __restrict__ wt) {
    int idx = blockIdx.x * 256 + threadIdx.x;   // 65536 total
    int k = idx >> 8, o = idx & 255;
    wt[idx] = (k < IN_C) ? w1l[o * IN_C + k] : w1r[o * IN_C + (k - IN_C)];
}

// GEMM1: h[N,256] = relu(A @ wt + b1), A = [agg1 | x] (N x 256 combined K).
#define BM 64
#define BN 64
#define BK 16
#define LDP (BM + 4)

__global__ __launch_bounds__(256) void gemm1(
    const float* __restrict__ x, const float* __restrict__ agg,
    const float* __restrict__ wt, const float* __restrict__ b1,
    float* __restrict__ h, int n_nodes) {
    __shared__ float As[BK][LDP];
    __shared__ float Bs[BK][LDP];

    const int tid = threadIdx.x;
    const int row0 = blockIdx.x * BM;
    const int col0 = blockIdx.y * BN;

    const int tx = tid & 15;
    const int ty = tid >> 4;
    float acc[4][4] = {};

    const int lrow = tid >> 2;
    const int lk4 = (tid & 3) * 4;
    const int bk = tid >> 4;
    const int bn4 = (tid & 15) * 4;

    int arow = row0 + lrow;
    if (arow >= n_nodes) arow = n_nodes - 1;

    for (int k0 = 0; k0 < 2 * IN_C; k0 += BK) {
        float4 av = (k0 < IN_C)
            ? *(const float4*)&agg[arow * IN_C + k0 + lk4]
            : *(const float4*)&x[arow * IN_C + (k0 - IN_C) + lk4];
        float4 bv = *(const float4*)&wt[(k0 + bk) * HID_C + col0 + bn4];

        __syncthreads();
        As[lk4 + 0][lrow] = av.x;
        As[lk4 + 1][lrow] = av.y;
        As[lk4 + 2][lrow] = av.z;
        As[lk4 + 3][lrow] = av.w;
        *(float4*)&Bs[bk][bn4] = bv;
        __syncthreads();

#pragma unroll
        for (int k = 0; k < BK; ++k) {
            float4 a4 = *(const float4*)&As[k][ty * 4];
            float4 b4 = *(const float4*)&Bs[k][tx * 4];
            float ar[4] = {a4.x, a4.y, a4.z, a4.w};
            float br[4] = {b4.x, b4.y, b4.z, b4.w};
#pragma unroll
            for (int i = 0; i < 4; ++i)
#pragma unroll
                for (int j = 0; j < 4; ++j) acc[i][j] = fmaf(ar[i], br[j], acc[i][j]);
        }
    }

    const float4 bias = *(const float4*)&b1[col0 + tx * 4];
#pragma unroll
    for (int i = 0; i < 4; ++i) {
        int r = row0 + ty * 4 + i;
        if (r < n_nodes) {
            float4 o;
            o.x = fmaxf(acc[i][0] + bias.x, 0.0f);
            o.y = fmaxf(acc[i][1] + bias.y, 0.0f);
            o.z = fmaxf(acc[i][2] + bias.z, 0.0f);
            o.w = fmaxf(acc[i][3] + bias.w, 0.0f);
            *(float4*)&h[r * HID_C + col0 + tx * 4] = o;
        }
    }
}

// ---- Layer 2 ---------------------------------------------------------------

// One pass over h: p = h @ W2l^T, r = h @ W2r^T (both N x 2).
__global__ __launch_bounds__(256) void proj2(
    const float* __restrict__ h, const float* __restrict__ w2l,
    const float* __restrict__ w2r, float* __restrict__ p,
    float* __restrict__ r, int n) {
    int node = blockIdx.x * 4 + (threadIdx.x >> 6);
    int lane = threadIdx.x & 63;
    if (node >= n) return;
    float4 h4 = *(const float4*)&h[node * HID_C + lane * 4];
    float4 l0 = *(const float4*)&w2l[0 * HID_C + lane * 4];
    float4 l1 = *(const float4*)&w2l[1 * HID_C + lane * 4];
    float4 r0 = *(const float4*)&w2r[0 * HID_C + lane * 4];
    float4 r1 = *(const float4*)&w2r[1 * HID_C + lane * 4];
    float s0 = h4.x * l0.x + h4.y * l0.y + h4.z * l0.z + h4.w * l0.w;
    float s1 = h4.x * l1.x + h4.y * l1.y + h4.z * l1.z + h4.w * l1.w;
    float s2 = h4.x * r0.x + h4.y * r0.y + h4.z * r0.z + h4.w * r0.w;
    float s3 = h4.x * r1.x + h4.y * r1.y + h4.z * r1.z + h4.w * r1.w;
#pragma unroll
    for (int off = 32; off > 0; off >>= 1) {
        s0 += __shfl_down(s0, off);
        s1 += __shfl_down(s1, off);
        s2 += __shfl_down(s2, off);
        s3 += __shfl_down(s3, off);
    }
    if (lane == 0) {
        p[node * 2 + 0] = s0;
        p[node * 2 + 1] = s1;
        r[node * 2 + 0] = s2;
        r[node * 2 + 1] = s3;
    }
}

// Scatter only 2 floats/edge into L2-resident agg2 (N x 2 = 400 KB).
__global__ void scatter_p(const int* __restrict__ ei, const float* __restrict__ p,
                          float* __restrict__ agg2, int E_) {
    int e = blockIdx.x * 256 + threadIdx.x;
    if (e >= E_) return;
    int src = ei[e];
    int dst = ei[E_ + e];
    float2 v = *(const float2*)&p[src * 2];
    unsafeAtomicAdd(&agg2[dst * 2 + 0], v.x);
    unsafeAtomicAdd(&agg2[dst * 2 + 1], v.y);
}

__global__ void finalize(const float* __restrict__ agg2, const float* __restrict__ r,
                         const int* __restrict__ rowptr, const float* __restrict__ b2,
                         float* __restrict__ out, int n) {
    int i = blockIdx.x * 256 + threadIdx.x;
    if (i >= n) return;
    float inv = 1.0f / (float)max(rowptr[i + 1] - rowptr[i], 1);
    out[i * 2 + 0] = agg2[i * 2 + 0] * inv + r[i * 2 + 0] + b2[0];
    out[i * 2 + 1] = agg2[i * 2 + 1] * inv + r[i * 2 + 1] + b2[1];
}

// ---- launch ----------------------------------------------------------------

extern "C" void kernel_launch(void* const* d_in, const int* in_sizes, int n_in,
                              void* d_out, int out_size, void* d_ws, size_t ws_size,
                              hipStream_t stream) {
    const float* x   = (const float*)d_in[0];
    const int*   ei  = (const int*)d_in[1];
    const float* W1l = (const float*)d_in[2];
    const float* b1  = (const float*)d_in[3];
    const float* W1r = (const float*)d_in[4];
    const float* W2l = (const float*)d_in[5];
    const float* b2  = (const float*)d_in[6];
    const float* W2r = (const float*)d_in[7];
    float* out = (float*)d_out;

    const int N_ = in_sizes[0] / IN_C;      // 50000
    const int E_ = in_sizes[1] / 2;         // 800000

    // Workspace layout (4-byte units), 16B-aligned chunks.
    char* wsb = (char*)d_ws;
    size_t off = 0;
    auto alloc = [&](size_t elems) {
        void* ptr = wsb + off;
        off += ((elems * 4 + 15) & ~(size_t)15);
        return ptr;
    };
    float* agg1   = (float*)alloc((size_t)N_ * IN_C);    // 25.6 MB
    float* h      = (float*)alloc((size_t)N_ * HID_C);   // 51.2 MB
    float* wt1    = (float*)alloc(2 * IN_C * HID_C);     // 256 KB
    int*   deg    = (int*)alloc(N_);                     // 200 KB
    int*   rowptr = (int*)alloc(N_ + 1);
    int*   cursor = (int*)alloc(N_);
    int*   elist  = (int*)alloc(E_);                     // 3.2 MB
    float* p      = (float*)alloc((size_t)N_ * 2);
    float* r      = (float*)alloc((size_t)N_ * 2);
    float* agg2   = (float*)alloc((size_t)N_ * 2);
    // total ~84 MB

    const int eb = (E_ + 255) / 256;

    // CSR build (shared by both layers' degree/mean)
    hipMemsetAsync(deg, 0, (size_t)N_ * sizeof(int), stream);
    hist_dst<<<eb, 256, 0, stream>>>(ei, deg, E_);
    transpose_w1<<<256, 256, 0, stream>>>(W1l, W1r, wt1);   // independent, overlaps nothing but cheap
    scan_deg<<<1, 1024, 0, stream>>>(deg, rowptr, cursor, N_);
    fill_csr<<<eb, 256, 0, stream>>>(ei, cursor, elist, E_);

    // Layer 1
    gather_agg1<<<(N_ + 3) / 4, 256, 0, stream>>>(rowptr, elist, x, agg1, N_);
    gemm1<<<dim3((N_ + BM - 1) / BM, HID_C / BN), 256, 0, stream>>>(
        x, agg1, wt1, b1, h, N_);

    // Layer 2 (linear commuted with mean: aggregate 2-dim projections)
    hipMemsetAsync(agg2, 0, (size_t)N_ * 2 * sizeof(float), stream);
    proj2<<<(N_ + 3) / 4, 256, 0, stream>>>(h, W2l, W2r, p, r, N_);
    scatter_p<<<eb, 256, 0, stream>>>(ei, p, agg2, E_);
    finalize<<<(N_ + 255) / 256, 256, 0, stream>>>(agg2, r, rowptr, b2, out, N_);
}

// Round 3
// 426.956 us; speedup vs baseline: 9.9240x; 1.1743x over previous
//
#include <hip/hip_runtime.h>
#include <hip/hip_bf16.h>

// ---------------------------------------------------------------------------
// GraphSAGE 2-layer: h = relu(mean_agg(x) @ W1l^T + b1 + x @ W1r^T)
//                    out = mean_agg(h) @ W2l^T + b2 + h @ W2r^T
// N=50000, E=800000, C: 128 -> 256 -> 2.
// Round 3: bf16 MFMA for layer-1 GEMM; bf16 gather reads; faster scan.
//   A = [mean_agg(x) | x]  (N x 256, bf16)   B = [W1l | W1r]  (256 x 256, bf16,
//   rows are output channels, k-contiguous -- exactly the MFMA B-frag layout).
// ---------------------------------------------------------------------------

#define IN_C 128
#define HID_C 256

typedef __attribute__((ext_vector_type(8))) short short8;   // 8 bf16 (4 VGPRs)
typedef __attribute__((ext_vector_type(4))) float f32x4;    // MFMA accumulator

static __device__ __forceinline__ unsigned short f2b(float f) {
    __hip_bfloat16 h = __float2bfloat16(f);
    return *(unsigned short*)&h;
}
static __device__ __forceinline__ float b2f(unsigned short u) {
    unsigned v = ((unsigned)u) << 16;
    return *(float*)&v;
}

// ---- CSR build -------------------------------------------------------------

__global__ void hist_dst(const int* __restrict__ ei, int* __restrict__ deg, int E_) {
    int e = blockIdx.x * 256 + threadIdx.x;
    if (e >= E_) return;
    atomicAdd(&deg[ei[E_ + e]], 1);
}

// Single-block exclusive scan, 8 elements/thread (7 chunks for N=50000).
__global__ __launch_bounds__(1024) void scan_deg(const int* __restrict__ deg,
                                                 int* __restrict__ rowptr,
                                                 int* __restrict__ cursor, int n) {
    __shared__ int wsum[16];
    __shared__ int carry_s;
    const int lane = threadIdx.x & 63;
    const int wid = threadIdx.x >> 6;
    if (threadIdx.x == 0) carry_s = 0;
    __syncthreads();
    for (int base = 0; base < n; base += 8192) {
        int i0 = base + threadIdx.x * 8;
        int v[8];
#pragma unroll
        for (int j = 0; j < 8; ++j) {
            int i = i0 + j;
            v[j] = (i < n) ? deg[i] : 0;
        }
        int s = 0;
#pragma unroll
        for (int j = 0; j < 8; ++j) { int t = v[j]; v[j] = s; s += t; }  // local excl
        int incl = s;
#pragma unroll
        for (int off = 1; off < 64; off <<= 1) {
            int t = __shfl_up(incl, off);
            if (lane >= off) incl += t;
        }
        if (lane == 63) wsum[wid] = incl;
        __syncthreads();
        int woff = 0;
        for (int w = 0; w < 16; ++w)
            if (w < wid) woff += wsum[w];
        int texcl = carry_s + woff + incl - s;
#pragma unroll
        for (int j = 0; j < 8; ++j) {
            int i = i0 + j;
            if (i < n) { rowptr[i] = texcl + v[j]; cursor[i] = texcl + v[j]; }
        }
        __syncthreads();
        if (threadIdx.x == 1023) carry_s += woff + incl;
        __syncthreads();
    }
    if (threadIdx.x == 0) rowptr[n] = carry_s;
}

__global__ void fill_csr(const int* __restrict__ ei, int* __restrict__ cursor,
                         int* __restrict__ elist, int E_) {
    int e = blockIdx.x * 256 + threadIdx.x;
    if (e >= E_) return;
    int dst = ei[E_ + e];
    int pos = atomicAdd(&cursor[dst], 1);
    elist[pos] = ei[e];   // store src
}

// ---- bf16 conversions ------------------------------------------------------

// xh = bf16(x); also fill right half of A (cols 128..255).
__global__ void convert_x(const float* __restrict__ x, unsigned int* __restrict__ xh,
                          unsigned int* __restrict__ Abf, int npairs /* N*64 */) {
    int t = blockIdx.x * 256 + threadIdx.x;
    if (t >= npairs) return;
    float2 v = *(const float2*)&x[(size_t)t * 2];
    unsigned int o = ((unsigned)f2b(v.y) << 16) | f2b(v.x);
    xh[t] = o;
    int node = t >> 6, g = t & 63;
    Abf[(size_t)node * 128 + 64 + g] = o;   // A row = 256 bf16 = 128 uints
}

// Bg[o][k] = bf16(k<128 ? W1l[o][k] : W1r[o][k-128]); 256x256, k-contiguous.
__global__ void convert_w1(const float* __restrict__ w1l,
                           const float* __restrict__ w1r,
                           unsigned short* __restrict__ Bg) {
    int idx = blockIdx.x * 256 + threadIdx.x;   // 65536
    int o = idx >> 8, k = idx & 255;
    float f = (k < IN_C) ? w1l[o * IN_C + k] : w1r[o * IN_C + (k - IN_C)];
    Bg[idx] = f2b(f);
}

// ---- Layer-1 aggregation: one wave per node, bf16 gather, fp32 accumulate --

__global__ __launch_bounds__(256) void gather_agg1(
    const int* __restrict__ rowptr, const int* __restrict__ elist,
    const unsigned int* __restrict__ xh, unsigned int* __restrict__ Abf, int n) {
    int node = blockIdx.x * 4 + (threadIdx.x >> 6);
    int lane = threadIdx.x & 63;
    if (node >= n) return;
    int beg = rowptr[node], end = rowptr[node + 1];
    float sx = 0.0f, sy = 0.0f;
    int e = beg;
    for (; e + 1 < end; e += 2) {
        unsigned int u0 = xh[(size_t)elist[e] * 64 + lane];
        unsigned int u1 = xh[(size_t)elist[e + 1] * 64 + lane];
        sx += b2f(u0 & 0xffff) + b2f(u1 & 0xffff);
        sy += b2f(u0 >> 16) + b2f(u1 >> 16);
    }
    if (e < end) {
        unsigned int u0 = xh[(size_t)elist[e] * 64 + lane];
        sx += b2f(u0 & 0xffff);
        sy += b2f(u0 >> 16);
    }
    float inv = 1.0f / (float)max(end - beg, 1);
    unsigned int o = ((unsigned)f2b(sy * inv) << 16) | f2b(sx * inv);
    Abf[(size_t)node * 128 + lane] = o;   // left half of A row
}

// ---- Layer-1 GEMM: h = relu(A @ Bg^T + b1), MFMA bf16 ----------------------
// Block: 128 rows x 128 cols, 256 threads = 4 waves (2x2 of 64x64 per wave).
// K = 256, BK = 64 (4 iterations). LDS stride 72 shorts (2-way conflicts only).

#define LSTR 72

__global__ __launch_bounds__(256) void gemm1_mfma(
    const unsigned short* __restrict__ Abf, const unsigned short* __restrict__ Bg,
    const float* __restrict__ b1, float* __restrict__ h, int nn) {
    __shared__ short As[128 * LSTR];
    __shared__ short Bs[128 * LSTR];

    const int tid = threadIdx.x;
    const int lane = tid & 63;
    const int wid = tid >> 6;
    const int wm = wid >> 1, wn = wid & 1;
    const int row0 = blockIdx.x * 128;
    const int col0 = blockIdx.y * 128;

    // staging mapping: thread t -> row t>>1, k-chunk (t&1)*32  (32 bf16 = 64 B)
    const int srow = tid >> 1;
    const int skc = (tid & 1) * 32;
    int arow = row0 + srow;
    if (arow >= nn) arow = nn - 1;
    const size_t agoff = (size_t)arow * 256 + skc;
    const size_t bgoff = (size_t)(col0 + srow) * 256 + skc;

    f32x4 acc[4][4];
#pragma unroll
    for (int i = 0; i < 4; ++i)
#pragma unroll
        for (int j = 0; j < 4; ++j) acc[i][j] = (f32x4){0.f, 0.f, 0.f, 0.f};

    const int quad = lane >> 4;     // 0..3
    const int l16 = lane & 15;

    for (int k0 = 0; k0 < 256; k0 += 64) {
        const uint4* ga = (const uint4*)(Abf + agoff + k0);
        const uint4* gb = (const uint4*)(Bg + bgoff + k0);
        uint4 va0 = ga[0], va1 = ga[1], va2 = ga[2], va3 = ga[3];
        uint4 vb0 = gb[0], vb1 = gb[1], vb2 = gb[2], vb3 = gb[3];

        __syncthreads();   // previous iteration's LDS reads complete
        uint4* la = (uint4*)&As[srow * LSTR + skc];
        uint4* lb = (uint4*)&Bs[srow * LSTR + skc];
        la[0] = va0; la[1] = va1; la[2] = va2; la[3] = va3;
        lb[0] = vb0; lb[1] = vb1; lb[2] = vb2; lb[3] = vb3;
        __syncthreads();

#pragma unroll
        for (int kb = 0; kb < 2; ++kb) {
            short8 af[4], bf[4];
#pragma unroll
            for (int mt = 0; mt < 4; ++mt)
                af[mt] = *(const short8*)&As[(wm * 64 + mt * 16 + l16) * LSTR + kb * 32 + quad * 8];
#pragma unroll
            for (int nt = 0; nt < 4; ++nt)
                bf[nt] = *(const short8*)&Bs[(wn * 64 + nt * 16 + l16) * LSTR + kb * 32 + quad * 8];
#pragma unroll
            for (int mt = 0; mt < 4; ++mt)
#pragma unroll
                for (int nt = 0; nt < 4; ++nt)
                    acc[mt][nt] = __builtin_amdgcn_mfma_f32_16x16x32_bf16(
                        af[mt], bf[nt], acc[mt][nt], 0, 0, 0);
        }
    }

    // epilogue: C/D layout col = lane&15, row = quad*4 + reg  (m89-verified)
    const int rbase = row0 + wm * 64 + quad * 4;
    const int cbase = col0 + wn * 64 + l16;
#pragma unroll
    for (int nt = 0; nt < 4; ++nt) {
        const int col = cbase + nt * 16;
        const float bias = b1[col];
#pragma unroll
        for (int mt = 0; mt < 4; ++mt) {
#pragma unroll
            for (int r = 0; r < 4; ++r) {
                int row = rbase + mt * 16 + r;
                if (row < nn)
                    h[(size_t)row * HID_C + col] = fmaxf(acc[mt][nt][r] + bias, 0.0f);
            }
        }
    }
}

// ---- Layer 2 ---------------------------------------------------------------

// p = h @ W2l^T, r = h @ W2r^T (both N x 2); one wave per node.
__global__ __launch_bounds__(256) void proj2(
    const float* __restrict__ h, const float* __restrict__ w2l,
    const float* __restrict__ w2r, float* __restrict__ p,
    float* __restrict__ r, int n) {
    int node = blockIdx.x * 4 + (threadIdx.x >> 6);
    int lane = threadIdx.x & 63;
    if (node >= n) return;
    float4 h4 = *(const float4*)&h[(size_t)node * HID_C + lane * 4];
    float4 l0 = *(const float4*)&w2l[0 * HID_C + lane * 4];
    float4 l1 = *(const float4*)&w2l[1 * HID_C + lane * 4];
    float4 r0 = *(const float4*)&w2r[0 * HID_C + lane * 4];
    float4 r1 = *(const float4*)&w2r[1 * HID_C + lane * 4];
    float s0 = h4.x * l0.x + h4.y * l0.y + h4.z * l0.z + h4.w * l0.w;
    float s1 = h4.x * l1.x + h4.y * l1.y + h4.z * l1.z + h4.w * l1.w;
    float s2 = h4.x * r0.x + h4.y * r0.y + h4.z * r0.z + h4.w * r0.w;
    float s3 = h4.x * r1.x + h4.y * r1.y + h4.z * r1.z + h4.w * r1.w;
#pragma unroll
    for (int off = 32; off > 0; off >>= 1) {
        s0 += __shfl_down(s0, off);
        s1 += __shfl_down(s1, off);
        s2 += __shfl_down(s2, off);
        s3 += __shfl_down(s3, off);
    }
    if (lane == 0) {
        p[node * 2 + 0] = s0;
        p[node * 2 + 1] = s1;
        r[node * 2 + 0] = s2;
        r[node * 2 + 1] = s3;
    }
}

// Scatter 2 floats/edge into L2-resident agg2 (N x 2 = 400 KB).
__global__ void scatter_p(const int* __restrict__ ei, const float* __restrict__ p,
                          float* __restrict__ agg2, int E_) {
    int e = blockIdx.x * 256 + threadIdx.x;
    if (e >= E_) return;
    int src = ei[e];
    int dst = ei[E_ + e];
    float2 v = *(const float2*)&p[src * 2];
    unsafeAtomicAdd(&agg2[dst * 2 + 0], v.x);
    unsafeAtomicAdd(&agg2[dst * 2 + 1], v.y);
}

__global__ void finalize(const float* __restrict__ agg2, const float* __restrict__ r,
                         const int* __restrict__ rowptr, const float* __restrict__ b2,
                         float* __restrict__ out, int n) {
    int i = blockIdx.x * 256 + threadIdx.x;
    if (i >= n) return;
    float inv = 1.0f / (float)max(rowptr[i + 1] - rowptr[i], 1);
    out[i * 2 + 0] = agg2[i * 2 + 0] * inv + r[i * 2 + 0] + b2[0];
    out[i * 2 + 1] = agg2[i * 2 + 1] * inv + r[i * 2 + 1] + b2[1];
}

// ---- launch ----------------------------------------------------------------

extern "C" void kernel_launch(void* const* d_in, const int* in_sizes, int n_in,
                              void* d_out, int out_size, void* d_ws, size_t ws_size,
                              hipStream_t stream) {
    const float* x   = (const float*)d_in[0];
    const int*   ei  = (const int*)d_in[1];
    const float* W1l = (const float*)d_in[2];
    const float* b1  = (const float*)d_in[3];
    const float* W1r = (const float*)d_in[4];
    const float* W2l = (const float*)d_in[5];
    const float* b2  = (const float*)d_in[6];
    const float* W2r = (const float*)d_in[7];
    float* out = (float*)d_out;

    const int N_ = in_sizes[0] / IN_C;      // 50000
    const int E_ = in_sizes[1] / 2;         // 800000

    char* wsb = (char*)d_ws;
    size_t off = 0;
    auto alloc = [&](size_t bytes) {
        void* ptr = wsb + off;
        off += ((bytes + 15) & ~(size_t)15);
        return ptr;
    };
    unsigned short* Abf = (unsigned short*)alloc((size_t)N_ * 256 * 2);  // 25.6 MB
    unsigned int*   xh  = (unsigned int*)alloc((size_t)N_ * 64 * 4);     // 12.8 MB
    float* h    = (float*)alloc((size_t)N_ * HID_C * 4);                 // 51.2 MB
    unsigned short* Bg = (unsigned short*)alloc(256 * 256 * 2);          // 128 KB
    int*   deg    = (int*)alloc((size_t)N_ * 4);
    int*   rowptr = (int*)alloc((size_t)(N_ + 1) * 4);
    int*   cursor = (int*)alloc((size_t)N_ * 4);
    int*   elist  = (int*)alloc((size_t)E_ * 4);                         // 3.2 MB
    float* p    = (float*)alloc((size_t)N_ * 2 * 4);
    float* r    = (float*)alloc((size_t)N_ * 2 * 4);
    float* agg2 = (float*)alloc((size_t)N_ * 2 * 4);
    // total ~95 MB

    const int eb = (E_ + 255) / 256;

    // CSR build + conversions
    hipMemsetAsync(deg, 0, (size_t)N_ * sizeof(int), stream);
    hist_dst<<<eb, 256, 0, stream>>>(ei, deg, E_);
    convert_x<<<(N_ * 64 + 255) / 256, 256, 0, stream>>>(x, xh, (unsigned int*)Abf, N_ * 64);
    convert_w1<<<256, 256, 0, stream>>>(W1l, W1r, Bg);
    scan_deg<<<1, 1024, 0, stream>>>(deg, rowptr, cursor, N_);
    fill_csr<<<eb, 256, 0, stream>>>(ei, cursor, elist, E_);

    // Layer 1
    gather_agg1<<<(N_ + 3) / 4, 256, 0, stream>>>(rowptr, elist, xh, (unsigned int*)Abf, N_);
    gemm1_mfma<<<dim3((N_ + 127) / 128, 2), 256, 0, stream>>>(Abf, Bg, b1, h, N_);

    // Layer 2 (linear commuted with mean)
    hipMemsetAsync(agg2, 0, (size_t)N_ * 2 * sizeof(float), stream);
    proj2<<<(N_ + 3) / 4, 256, 0, stream>>>(h, W2l, W2r, p, r, N_);
    scatter_p<<<eb, 256, 0, stream>>>(ei, p, agg2, E_);
    finalize<<<(N_ + 255) / 256, 256, 0, stream>>>(agg2, r, rowptr, b2, out, N_);
}

// Round 5
// 345.320 us; speedup vs baseline: 12.2701x; 1.2364x over previous
//
#include <hip/hip_runtime.h>
#include <hip/hip_bf16.h>

// ---------------------------------------------------------------------------
// GraphSAGE 2-layer: h = relu(mean_agg(x) @ W1l^T + b1 + x @ W1r^T)
//                    out = mean_agg(h) @ W2l^T + b2 + h @ W2r^T
// N=50000, E=800000, C: 128 -> 256 -> 2.
// Round 5 (= Round 4 + compile fix): kill ALL fp32 scatter atomics + never
// materialize h.
//  - Layer-2 projection fused into gemm1 epilogue (quad butterfly reduce,
//    plain partial stores) -> h (51 MB x2 traffic) eliminated.
//  - Layer-2 aggregation: CSR gather of 2-dim projections (no atomics).
// ---------------------------------------------------------------------------

#define IN_C 128
#define HID_C 256

typedef __attribute__((ext_vector_type(8))) short short8;   // 8 bf16 (4 VGPRs)
typedef __attribute__((ext_vector_type(4))) float f32x4;    // MFMA accumulator

static __device__ __forceinline__ unsigned short f2b(float f) {
    __hip_bfloat16 h = __float2bfloat16(f);
    return *(unsigned short*)&h;
}
static __device__ __forceinline__ float b2f(unsigned short u) {
    unsigned v = ((unsigned)u) << 16;
    return *(float*)&v;
}

// ---- CSR build -------------------------------------------------------------

__global__ void hist_dst(const int* __restrict__ ei, int* __restrict__ deg, int E_) {
    int e = blockIdx.x * 256 + threadIdx.x;
    if (e >= E_) return;
    atomicAdd(&deg[ei[E_ + e]], 1);
}

// Single-block exclusive scan, 8 elements/thread (7 chunks for N=50000).
__global__ __launch_bounds__(1024) void scan_deg(const int* __restrict__ deg,
                                                 int* __restrict__ rowptr,
                                                 int* __restrict__ cursor, int n) {
    __shared__ int wsum[16];
    __shared__ int carry_s;
    const int lane = threadIdx.x & 63;
    const int wid = threadIdx.x >> 6;
    if (threadIdx.x == 0) carry_s = 0;
    __syncthreads();
    for (int base = 0; base < n; base += 8192) {
        int i0 = base + threadIdx.x * 8;
        int v[8];
#pragma unroll
        for (int j = 0; j < 8; ++j) {
            int i = i0 + j;
            v[j] = (i < n) ? deg[i] : 0;
        }
        int s = 0;
#pragma unroll
        for (int j = 0; j < 8; ++j) { int t = v[j]; v[j] = s; s += t; }  // local excl
        int incl = s;
#pragma unroll
        for (int off = 1; off < 64; off <<= 1) {
            int t = __shfl_up(incl, off);
            if (lane >= off) incl += t;
        }
        if (lane == 63) wsum[wid] = incl;
        __syncthreads();
        int woff = 0;
        for (int w = 0; w < 16; ++w)
            if (w < wid) woff += wsum[w];
        int texcl = carry_s + woff + incl - s;
#pragma unroll
        for (int j = 0; j < 8; ++j) {
            int i = i0 + j;
            if (i < n) { rowptr[i] = texcl + v[j]; cursor[i] = texcl + v[j]; }
        }
        __syncthreads();
        if (threadIdx.x == 1023) carry_s += woff + incl;
        __syncthreads();
    }
    if (threadIdx.x == 0) rowptr[n] = carry_s;
}

__global__ void fill_csr(const int* __restrict__ ei, int* __restrict__ cursor,
                         int* __restrict__ elist, int E_) {
    int e = blockIdx.x * 256 + threadIdx.x;
    if (e >= E_) return;
    int dst = ei[E_ + e];
    int pos = atomicAdd(&cursor[dst], 1);
    elist[pos] = ei[e];   // store src
}

// ---- bf16 conversions ------------------------------------------------------

// xh = bf16(x); also fill right half of A (cols 128..255).
__global__ void convert_x(const float* __restrict__ x, unsigned int* __restrict__ xh,
                          unsigned int* __restrict__ Abf, int npairs /* N*64 */) {
    int t = blockIdx.x * 256 + threadIdx.x;
    if (t >= npairs) return;
    float2 v = *(const float2*)&x[(size_t)t * 2];
    unsigned int o = ((unsigned)f2b(v.y) << 16) | f2b(v.x);
    xh[t] = o;
    int node = t >> 6, g = t & 63;
    Abf[(size_t)node * 128 + 64 + g] = o;   // A row = 256 bf16 = 128 uints
}

// Bg[o][k] = bf16(k<128 ? W1l[o][k] : W1r[o][k-128]); 256x256, k-contiguous.
__global__ void convert_w1(const float* __restrict__ w1l,
                           const float* __restrict__ w1r,
                           unsigned short* __restrict__ Bg) {
    int idx = blockIdx.x * 256 + threadIdx.x;   // 65536
    int o = idx >> 8, k = idx & 255;
    float f = (k < IN_C) ? w1l[o * IN_C + k] : w1r[o * IN_C + (k - IN_C)];
    Bg[idx] = f2b(f);
}

// ---- Layer-1 aggregation: one wave per node, bf16 gather, fp32 accumulate --

__global__ __launch_bounds__(256) void gather_agg1(
    const int* __restrict__ rowptr, const int* __restrict__ elist,
    const unsigned int* __restrict__ xh, unsigned int* __restrict__ Abf, int n) {
    int node = blockIdx.x * 4 + (threadIdx.x >> 6);
    int lane = threadIdx.x & 63;
    if (node >= n) return;
    int beg = rowptr[node], end = rowptr[node + 1];
    float sx = 0.0f, sy = 0.0f;
    int e = beg;
    for (; e + 1 < end; e += 2) {
        unsigned int u0 = xh[(size_t)elist[e] * 64 + lane];
        unsigned int u1 = xh[(size_t)elist[e + 1] * 64 + lane];
        sx += b2f(u0 & 0xffff) + b2f(u1 & 0xffff);
        sy += b2f(u0 >> 16) + b2f(u1 >> 16);
    }
    if (e < end) {
        unsigned int u0 = xh[(size_t)elist[e] * 64 + lane];
        sx += b2f(u0 & 0xffff);
        sy += b2f(u0 >> 16);
    }
    float inv = 1.0f / (float)max(end - beg, 1);
    unsigned int o = ((unsigned)f2b(sy * inv) << 16) | f2b(sx * inv);
    Abf[(size_t)node * 128 + lane] = o;   // left half of A row
}

// ---- Layer-1 GEMM + fused layer-2 projection -------------------------------
// Block: 128 rows x 128 cols, 256 threads = 4 waves (2x2 of 64x64 per wave).
// K = 256, BK = 64. After MFMA: hv = relu(acc + b1), project onto
// w2l[0],w2l[1],w2r[0],w2r[1]; butterfly-reduce 16 lanes/quad; store partials
// pr_part[row][cby][ch] (cby = blockIdx.y*2 + wn), each slot written once.

#define LSTR 72

__global__ __launch_bounds__(256) void gemm1_fused(
    const unsigned short* __restrict__ Abf, const unsigned short* __restrict__ Bg,
    const float* __restrict__ b1, const float* __restrict__ w2l,
    const float* __restrict__ w2r, float* __restrict__ pr_part, int nn) {
    __shared__ short As[128 * LSTR];
    __shared__ short Bs[128 * LSTR];

    const int tid = threadIdx.x;
    const int lane = tid & 63;
    const int wid = tid >> 6;
    const int wm = wid >> 1, wn = wid & 1;
    const int row0 = blockIdx.x * 128;
    const int col0 = blockIdx.y * 128;

    const int srow = tid >> 1;
    const int skc = (tid & 1) * 32;
    int arow = row0 + srow;
    if (arow >= nn) arow = nn - 1;
    const size_t agoff = (size_t)arow * 256 + skc;
    const size_t bgoff = (size_t)(col0 + srow) * 256 + skc;

    f32x4 acc[4][4];
#pragma unroll
    for (int i = 0; i < 4; ++i)
#pragma unroll
        for (int j = 0; j < 4; ++j) acc[i][j] = (f32x4){0.f, 0.f, 0.f, 0.f};

    const int quad = lane >> 4;     // 0..3
    const int l16 = lane & 15;

    for (int k0 = 0; k0 < 256; k0 += 64) {
        const uint4* ga = (const uint4*)(Abf + agoff + k0);
        const uint4* gb = (const uint4*)(Bg + bgoff + k0);
        uint4 va0 = ga[0], va1 = ga[1], va2 = ga[2], va3 = ga[3];
        uint4 vb0 = gb[0], vb1 = gb[1], vb2 = gb[2], vb3 = gb[3];

        __syncthreads();
        uint4* la = (uint4*)&As[srow * LSTR + skc];
        uint4* lb = (uint4*)&Bs[srow * LSTR + skc];
        la[0] = va0; la[1] = va1; la[2] = va2; la[3] = va3;
        lb[0] = vb0; lb[1] = vb1; lb[2] = vb2; lb[3] = vb3;
        __syncthreads();

#pragma unroll
        for (int kb = 0; kb < 2; ++kb) {
            short8 af[4], bf[4];
#pragma unroll
            for (int mt = 0; mt < 4; ++mt)
                af[mt] = *(const short8*)&As[(wm * 64 + mt * 16 + l16) * LSTR + kb * 32 + quad * 8];
#pragma unroll
            for (int nt = 0; nt < 4; ++nt)
                bf[nt] = *(const short8*)&Bs[(wn * 64 + nt * 16 + l16) * LSTR + kb * 32 + quad * 8];
#pragma unroll
            for (int mt = 0; mt < 4; ++mt)
#pragma unroll
                for (int nt = 0; nt < 4; ++nt)
                    acc[mt][nt] = __builtin_amdgcn_mfma_f32_16x16x32_bf16(
                        af[mt], bf[nt], acc[mt][nt], 0, 0, 0);
        }
    }

    // ---- fused projection epilogue (no h materialization) ----
    // C/D layout: col = l16, row = quad*4 + reg (m89-verified).
    const int cbase = col0 + wn * 64 + l16;
    const int cby = blockIdx.y * 2 + wn;   // 0..3 column slot
#pragma unroll
    for (int half = 0; half < 2; ++half) {
        const float* wA = half ? w2r : w2l;          // rows 0,1 of W2{l,r}
        f32x4 part[2][4];
#pragma unroll
        for (int c = 0; c < 2; ++c)
#pragma unroll
            for (int mt = 0; mt < 4; ++mt) part[c][mt] = (f32x4){0.f, 0.f, 0.f, 0.f};
#pragma unroll
        for (int nt = 0; nt < 4; ++nt) {
            const int col = cbase + nt * 16;
            const float bias = b1[col];
            const float w0 = wA[col];
            const float w1 = wA[HID_C + col];
#pragma unroll
            for (int mt = 0; mt < 4; ++mt)
#pragma unroll
                for (int r = 0; r < 4; ++r) {
                    float hv = fmaxf(acc[mt][nt][r] + bias, 0.0f);
                    part[0][mt][r] += hv * w0;
                    part[1][mt][r] += hv * w1;
                }
        }
        // butterfly across the 16 lanes of this quad (masks 1..8 stay in-quad)
#pragma unroll
        for (int c = 0; c < 2; ++c)
#pragma unroll
            for (int mt = 0; mt < 4; ++mt)
#pragma unroll
                for (int r = 0; r < 4; ++r)
#pragma unroll
                    for (int m = 1; m < 16; m <<= 1)
                        part[c][mt][r] += __shfl_xor(part[c][mt][r], m);
        // lanes 0..7 of each quad store: ch2 = l16&1, mt = l16>>1
        if (l16 < 8) {
            const int ch2 = l16 & 1;
            const int mts = l16 >> 1;
#pragma unroll
            for (int r = 0; r < 4; ++r) {
                int row = row0 + wm * 64 + quad * 4 + mts * 16 + r;
                if (row < nn)
                    pr_part[(size_t)row * 16 + cby * 4 + half * 2 + ch2] =
                        part[ch2][mts][r];
            }
        }
    }
}

// ---- Layer 2 tail ----------------------------------------------------------

// Sum the 4 column-slot partials per node: p2 = projection for gather,
// rs = self (lin_r) projection.
__global__ void combine2(const float* __restrict__ pr_part,
                         float2* __restrict__ p2, float2* __restrict__ rs, int n) {
    int i = blockIdx.x * 256 + threadIdx.x;
    if (i >= n) return;
    const float4* q = (const float4*)(pr_part + (size_t)i * 16);
    float4 a = q[0], b = q[1], c = q[2], d = q[3];
    p2[i] = make_float2(a.x + b.x + c.x + d.x, a.y + b.y + c.y + d.y);
    rs[i] = make_float2(a.z + b.z + c.z + d.z, a.w + b.w + c.w + d.w);
}

// CSR gather of 2-dim projections (no atomics), + bias, -> out.
__global__ void gather_fin(const int* __restrict__ rowptr, const int* __restrict__ elist,
                           const float2* __restrict__ p2, const float2* __restrict__ rs,
                           const float* __restrict__ b2, float* __restrict__ out, int n) {
    int i = blockIdx.x * 256 + threadIdx.x;
    if (i >= n) return;
    int beg = rowptr[i], end = rowptr[i + 1];
    float s0 = 0.0f, s1 = 0.0f;
    for (int e = beg; e < end; ++e) {
        float2 v = p2[elist[e]];
        s0 += v.x; s1 += v.y;
    }
    float inv = 1.0f / (float)max(end - beg, 1);
    float2 self = rs[i];
    out[i * 2 + 0] = s0 * inv + self.x + b2[0];
    out[i * 2 + 1] = s1 * inv + self.y + b2[1];
}

// ---- launch ----------------------------------------------------------------

extern "C" void kernel_launch(void* const* d_in, const int* in_sizes, int n_in,
                              void* d_out, int out_size, void* d_ws, size_t ws_size,
                              hipStream_t stream) {
    const float* x   = (const float*)d_in[0];
    const int*   ei  = (const int*)d_in[1];
    const float* W1l = (const float*)d_in[2];
    const float* b1  = (const float*)d_in[3];
    const float* W1r = (const float*)d_in[4];
    const float* W2l = (const float*)d_in[5];
    const float* b2  = (const float*)d_in[6];
    const float* W2r = (const float*)d_in[7];
    float* out = (float*)d_out;

    const int N_ = in_sizes[0] / IN_C;      // 50000
    const int E_ = in_sizes[1] / 2;         // 800000

    char* wsb = (char*)d_ws;
    size_t off = 0;
    auto alloc = [&](size_t bytes) {
        void* ptr = wsb + off;
        off += ((bytes + 15) & ~(size_t)15);
        return ptr;
    };
    unsigned short* Abf = (unsigned short*)alloc((size_t)N_ * 256 * 2);  // 25.6 MB
    unsigned int*   xh  = (unsigned int*)alloc((size_t)N_ * 64 * 4);     // 12.8 MB
    unsigned short* Bg  = (unsigned short*)alloc(256 * 256 * 2);         // 128 KB
    float* pr_part = (float*)alloc((size_t)N_ * 16 * 4);                 // 3.2 MB
    int*   deg    = (int*)alloc((size_t)N_ * 4);
    int*   rowptr = (int*)alloc((size_t)(N_ + 1) * 4);
    int*   cursor = (int*)alloc((size_t)N_ * 4);
    int*   elist  = (int*)alloc((size_t)E_ * 4);                         // 3.2 MB
    float2* p2 = (float2*)alloc((size_t)N_ * 2 * 4);
    float2* rs = (float2*)alloc((size_t)N_ * 2 * 4);
    // total ~46 MB

    const int eb = (E_ + 255) / 256;

    // CSR build + conversions
    hipMemsetAsync(deg, 0, (size_t)N_ * sizeof(int), stream);
    hist_dst<<<eb, 256, 0, stream>>>(ei, deg, E_);
    convert_x<<<(N_ * 64 + 255) / 256, 256, 0, stream>>>(x, xh, (unsigned int*)Abf, N_ * 64);
    convert_w1<<<256, 256, 0, stream>>>(W1l, W1r, Bg);
    scan_deg<<<1, 1024, 0, stream>>>(deg, rowptr, cursor, N_);
    fill_csr<<<eb, 256, 0, stream>>>(ei, cursor, elist, E_);

    // Layer 1 GEMM with fused layer-2 projection
    gather_agg1<<<(N_ + 3) / 4, 256, 0, stream>>>(rowptr, elist, xh, (unsigned int*)Abf, N_);
    gemm1_fused<<<dim3((N_ + 127) / 128, 2), 256, 0, stream>>>(
        Abf, Bg, b1, W2l, W2r, pr_part, N_);

    // Layer 2 tail: combine partials, CSR gather, bias
    combine2<<<(N_ + 255) / 256, 256, 0, stream>>>(pr_part, p2, rs, N_);
    gather_fin<<<(N_ + 255) / 256, 256, 0, stream>>>(rowptr, elist, p2, rs, b2, out, N_);
}

// Round 6
// 292.197 us; speedup vs baseline: 14.5008x; 1.1818x over previous
//
#include <hip/hip_runtime.h>
#include <hip/hip_bf16.h>

// ---------------------------------------------------------------------------
// GraphSAGE 2-layer: h = relu(mean_agg(x) @ W1l^T + b1 + x @ W1r^T)
//                    out = mean_agg(h) @ W2l^T + b2 + h @ W2r^T
// N=50000, E=800000, C: 128 -> 256 -> 2.
// Round 6: replace single-block scan (69 us, 0.17% occupancy) with a 3-phase
// hierarchical scan (13 blocks x 4096 elems; ~3 us/phase). Rest unchanged:
//  - layer-1 agg: CSR gather (bf16); layer-1 GEMM: MFMA bf16 with fused
//    layer-2 projection epilogue (h never materialized);
//  - layer-2 agg: CSR gather of 2-dim projections (no fp32 atomics anywhere).
// ---------------------------------------------------------------------------

#define IN_C 128
#define HID_C 256
#define SCAN_CHUNK 4096   // elems per scan block (1024 thr x 4)

typedef __attribute__((ext_vector_type(8))) short short8;   // 8 bf16 (4 VGPRs)
typedef __attribute__((ext_vector_type(4))) float f32x4;    // MFMA accumulator

static __device__ __forceinline__ unsigned short f2b(float f) {
    __hip_bfloat16 h = __float2bfloat16(f);
    return *(unsigned short*)&h;
}
static __device__ __forceinline__ float b2f(unsigned short u) {
    unsigned v = ((unsigned)u) << 16;
    return *(float*)&v;
}

// ---- CSR build -------------------------------------------------------------

__global__ void hist_dst(const int* __restrict__ ei, int* __restrict__ deg, int E_) {
    int e = blockIdx.x * 256 + threadIdx.x;
    if (e >= E_) return;
    atomicAdd(&deg[ei[E_ + e]], 1);
}

// Phase 1: block-local exclusive scan (4 elems/thread, int4 coalesced),
// per-element result -> rowptr (block-relative), block total -> bsum.
__global__ __launch_bounds__(1024) void scan_p1(const int* __restrict__ deg,
                                                int* __restrict__ rowptr,
                                                int* __restrict__ bsum, int n) {
    __shared__ int wsum[16];
    const int tid = threadIdx.x;
    const int lane = tid & 63;
    const int wid = tid >> 6;
    const int i0 = blockIdx.x * SCAN_CHUNK + tid * 4;

    int4 v = make_int4(0, 0, 0, 0);
    if (i0 + 3 < n) v = *(const int4*)&deg[i0];
    else {
        if (i0 + 0 < n) v.x = deg[i0 + 0];
        if (i0 + 1 < n) v.y = deg[i0 + 1];
        if (i0 + 2 < n) v.z = deg[i0 + 2];
        if (i0 + 3 < n) v.w = deg[i0 + 3];
    }
    const int s = v.x + v.y + v.z + v.w;

    int incl = s;
#pragma unroll
    for (int off = 1; off < 64; off <<= 1) {
        int t = __shfl_up(incl, off);
        if (lane >= off) incl += t;
    }
    if (lane == 63) wsum[wid] = incl;
    __syncthreads();
    int woff = 0;
    for (int w = 0; w < 16; ++w)
        if (w < wid) woff += wsum[w];
    const int texcl = woff + incl - s;   // block-relative exclusive prefix

    int4 o;
    o.x = texcl;
    o.y = texcl + v.x;
    o.z = texcl + v.x + v.y;
    o.w = texcl + v.x + v.y + v.z;
    if (i0 + 3 < n) *(int4*)&rowptr[i0] = o;
    else {
        if (i0 + 0 < n) rowptr[i0 + 0] = o.x;
        if (i0 + 1 < n) rowptr[i0 + 1] = o.y;
        if (i0 + 2 < n) rowptr[i0 + 2] = o.z;
        if (i0 + 3 < n) rowptr[i0 + 3] = o.w;
    }
    if (tid == 1023) bsum[blockIdx.x] = woff + incl;   // block total
}

// Phase 2: one wave scans block totals (nb <= 64) -> boff; total -> rowptr[n].
__global__ __launch_bounds__(64) void scan_p2(const int* __restrict__ bsum,
                                              int* __restrict__ boff,
                                              int* __restrict__ rowptr,
                                              int nb, int n) {
    const int tid = threadIdx.x;
    int v = (tid < nb) ? bsum[tid] : 0;
    int incl = v;
#pragma unroll
    for (int off = 1; off < 64; off <<= 1) {
        int t = __shfl_up(incl, off);
        if (tid >= off) incl += t;
    }
    if (tid < nb) boff[tid] = incl - v;
    if (tid == 63) rowptr[n] = incl;   // grand total
}

// Phase 3: add block offset, emit final rowptr + cursor copy.
__global__ __launch_bounds__(1024) void scan_p3(int* __restrict__ rowptr,
                                                int* __restrict__ cursor,
                                                const int* __restrict__ boff, int n) {
    const int i0 = blockIdx.x * SCAN_CHUNK + threadIdx.x * 4;
    const int add = boff[blockIdx.x];
    if (i0 + 3 < n) {
        int4 v = *(const int4*)&rowptr[i0];
        v.x += add; v.y += add; v.z += add; v.w += add;
        *(int4*)&rowptr[i0] = v;
        *(int4*)&cursor[i0] = v;
    } else {
#pragma unroll
        for (int j = 0; j < 4; ++j) {
            int i = i0 + j;
            if (i < n) { int t = rowptr[i] + add; rowptr[i] = t; cursor[i] = t; }
        }
    }
}

__global__ void fill_csr(const int* __restrict__ ei, int* __restrict__ cursor,
                         int* __restrict__ elist, int E_) {
    int e = blockIdx.x * 256 + threadIdx.x;
    if (e >= E_) return;
    int dst = ei[E_ + e];
    int pos = atomicAdd(&cursor[dst], 1);
    elist[pos] = ei[e];   // store src
}

// ---- bf16 conversions ------------------------------------------------------

// xh = bf16(x); also fill right half of A (cols 128..255).
__global__ void convert_x(const float* __restrict__ x, unsigned int* __restrict__ xh,
                          unsigned int* __restrict__ Abf, int npairs /* N*64 */) {
    int t = blockIdx.x * 256 + threadIdx.x;
    if (t >= npairs) return;
    float2 v = *(const float2*)&x[(size_t)t * 2];
    unsigned int o = ((unsigned)f2b(v.y) << 16) | f2b(v.x);
    xh[t] = o;
    int node = t >> 6, g = t & 63;
    Abf[(size_t)node * 128 + 64 + g] = o;   // A row = 256 bf16 = 128 uints
}

// Bg[o][k] = bf16(k<128 ? W1l[o][k] : W1r[o][k-128]); 256x256, k-contiguous.
__global__ void convert_w1(const float* __restrict__ w1l,
                           const float* __restrict__ w1r,
                           unsigned short* __restrict__ Bg) {
    int idx = blockIdx.x * 256 + threadIdx.x;   // 65536
    int o = idx >> 8, k = idx & 255;
    float f = (k < IN_C) ? w1l[o * IN_C + k] : w1r[o * IN_C + (k - IN_C)];
    Bg[idx] = f2b(f);
}

// ---- Layer-1 aggregation: one wave per node, bf16 gather, fp32 accumulate --

__global__ __launch_bounds__(256) void gather_agg1(
    const int* __restrict__ rowptr, const int* __restrict__ elist,
    const unsigned int* __restrict__ xh, unsigned int* __restrict__ Abf, int n) {
    int node = blockIdx.x * 4 + (threadIdx.x >> 6);
    int lane = threadIdx.x & 63;
    if (node >= n) return;
    int beg = rowptr[node], end = rowptr[node + 1];
    float sx = 0.0f, sy = 0.0f;
    int e = beg;
    for (; e + 1 < end; e += 2) {
        unsigned int u0 = xh[(size_t)elist[e] * 64 + lane];
        unsigned int u1 = xh[(size_t)elist[e + 1] * 64 + lane];
        sx += b2f(u0 & 0xffff) + b2f(u1 & 0xffff);
        sy += b2f(u0 >> 16) + b2f(u1 >> 16);
    }
    if (e < end) {
        unsigned int u0 = xh[(size_t)elist[e] * 64 + lane];
        sx += b2f(u0 & 0xffff);
        sy += b2f(u0 >> 16);
    }
    float inv = 1.0f / (float)max(end - beg, 1);
    unsigned int o = ((unsigned)f2b(sy * inv) << 16) | f2b(sx * inv);
    Abf[(size_t)node * 128 + lane] = o;   // left half of A row
}

// ---- Layer-1 GEMM + fused layer-2 projection -------------------------------
// Block: 128 rows x 128 cols, 256 threads = 4 waves (2x2 of 64x64 per wave).
// K = 256, BK = 64. After MFMA: hv = relu(acc + b1), project onto
// w2l[0],w2l[1],w2r[0],w2r[1]; butterfly-reduce 16 lanes/quad; store partials
// pr_part[row][cby][ch] (cby = blockIdx.y*2 + wn), each slot written once.

#define LSTR 72

__global__ __launch_bounds__(256) void gemm1_fused(
    const unsigned short* __restrict__ Abf, const unsigned short* __restrict__ Bg,
    const float* __restrict__ b1, const float* __restrict__ w2l,
    const float* __restrict__ w2r, float* __restrict__ pr_part, int nn) {
    __shared__ short As[128 * LSTR];
    __shared__ short Bs[128 * LSTR];

    const int tid = threadIdx.x;
    const int lane = tid & 63;
    const int wid = tid >> 6;
    const int wm = wid >> 1, wn = wid & 1;
    const int row0 = blockIdx.x * 128;
    const int col0 = blockIdx.y * 128;

    const int srow = tid >> 1;
    const int skc = (tid & 1) * 32;
    int arow = row0 + srow;
    if (arow >= nn) arow = nn - 1;
    const size_t agoff = (size_t)arow * 256 + skc;
    const size_t bgoff = (size_t)(col0 + srow) * 256 + skc;

    f32x4 acc[4][4];
#pragma unroll
    for (int i = 0; i < 4; ++i)
#pragma unroll
        for (int j = 0; j < 4; ++j) acc[i][j] = (f32x4){0.f, 0.f, 0.f, 0.f};

    const int quad = lane >> 4;     // 0..3
    const int l16 = lane & 15;

    for (int k0 = 0; k0 < 256; k0 += 64) {
        const uint4* ga = (const uint4*)(Abf + agoff + k0);
        const uint4* gb = (const uint4*)(Bg + bgoff + k0);
        uint4 va0 = ga[0], va1 = ga[1], va2 = ga[2], va3 = ga[3];
        uint4 vb0 = gb[0], vb1 = gb[1], vb2 = gb[2], vb3 = gb[3];

        __syncthreads();
        uint4* la = (uint4*)&As[srow * LSTR + skc];
        uint4* lb = (uint4*)&Bs[srow * LSTR + skc];
        la[0] = va0; la[1] = va1; la[2] = va2; la[3] = va3;
        lb[0] = vb0; lb[1] = vb1; lb[2] = vb2; lb[3] = vb3;
        __syncthreads();

#pragma unroll
        for (int kb = 0; kb < 2; ++kb) {
            short8 af[4], bf[4];
#pragma unroll
            for (int mt = 0; mt < 4; ++mt)
                af[mt] = *(const short8*)&As[(wm * 64 + mt * 16 + l16) * LSTR + kb * 32 + quad * 8];
#pragma unroll
            for (int nt = 0; nt < 4; ++nt)
                bf[nt] = *(const short8*)&Bs[(wn * 64 + nt * 16 + l16) * LSTR + kb * 32 + quad * 8];
#pragma unroll
            for (int mt = 0; mt < 4; ++mt)
#pragma unroll
                for (int nt = 0; nt < 4; ++nt)
                    acc[mt][nt] = __builtin_amdgcn_mfma_f32_16x16x32_bf16(
                        af[mt], bf[nt], acc[mt][nt], 0, 0, 0);
        }
    }

    // ---- fused projection epilogue (no h materialization) ----
    // C/D layout: col = l16, row = quad*4 + reg (m89-verified).
    const int cbase = col0 + wn * 64 + l16;
    const int cby = blockIdx.y * 2 + wn;   // 0..3 column slot
#pragma unroll
    for (int half = 0; half < 2; ++half) {
        const float* wA = half ? w2r : w2l;          // rows 0,1 of W2{l,r}
        f32x4 part[2][4];
#pragma unroll
        for (int c = 0; c < 2; ++c)
#pragma unroll
            for (int mt = 0; mt < 4; ++mt) part[c][mt] = (f32x4){0.f, 0.f, 0.f, 0.f};
#pragma unroll
        for (int nt = 0; nt < 4; ++nt) {
            const int col = cbase + nt * 16;
            const float bias = b1[col];
            const float w0 = wA[col];
            const float w1 = wA[HID_C + col];
#pragma unroll
            for (int mt = 0; mt < 4; ++mt)
#pragma unroll
                for (int r = 0; r < 4; ++r) {
                    float hv = fmaxf(acc[mt][nt][r] + bias, 0.0f);
                    part[0][mt][r] += hv * w0;
                    part[1][mt][r] += hv * w1;
                }
        }
        // butterfly across the 16 lanes of this quad (masks 1..8 stay in-quad)
#pragma unroll
        for (int c = 0; c < 2; ++c)
#pragma unroll
            for (int mt = 0; mt < 4; ++mt)
#pragma unroll
                for (int r = 0; r < 4; ++r)
#pragma unroll
                    for (int m = 1; m < 16; m <<= 1)
                        part[c][mt][r] += __shfl_xor(part[c][mt][r], m);
        // lanes 0..7 of each quad store: ch2 = l16&1, mt = l16>>1
        if (l16 < 8) {
            const int ch2 = l16 & 1;
            const int mts = l16 >> 1;
#pragma unroll
            for (int r = 0; r < 4; ++r) {
                int row = row0 + wm * 64 + quad * 4 + mts * 16 + r;
                if (row < nn)
                    pr_part[(size_t)row * 16 + cby * 4 + half * 2 + ch2] =
                        part[ch2][mts][r];
            }
        }
    }
}

// ---- Layer 2 tail ----------------------------------------------------------

// Sum the 4 column-slot partials per node: p2 = projection for gather,
// rs = self (lin_r) projection.
__global__ void combine2(const float* __restrict__ pr_part,
                         float2* __restrict__ p2, float2* __restrict__ rs, int n) {
    int i = blockIdx.x * 256 + threadIdx.x;
    if (i >= n) return;
    const float4* q = (const float4*)(pr_part + (size_t)i * 16);
    float4 a = q[0], b = q[1], c = q[2], d = q[3];
    p2[i] = make_float2(a.x + b.x + c.x + d.x, a.y + b.y + c.y + d.y);
    rs[i] = make_float2(a.z + b.z + c.z + d.z, a.w + b.w + c.w + d.w);
}

// CSR gather of 2-dim projections (no atomics), + bias, -> out.
__global__ void gather_fin(const int* __restrict__ rowptr, const int* __restrict__ elist,
                           const float2* __restrict__ p2, const float2* __restrict__ rs,
                           const float* __restrict__ b2, float* __restrict__ out, int n) {
    int i = blockIdx.x * 256 + threadIdx.x;
    if (i >= n) return;
    int beg = rowptr[i], end = rowptr[i + 1];
    float s0 = 0.0f, s1 = 0.0f;
    for (int e = beg; e < end; ++e) {
        float2 v = p2[elist[e]];
        s0 += v.x; s1 += v.y;
    }
    float inv = 1.0f / (float)max(end - beg, 1);
    float2 self = rs[i];
    out[i * 2 + 0] = s0 * inv + self.x + b2[0];
    out[i * 2 + 1] = s1 * inv + self.y + b2[1];
}

// ---- launch ----------------------------------------------------------------

extern "C" void kernel_launch(void* const* d_in, const int* in_sizes, int n_in,
                              void* d_out, int out_size, void* d_ws, size_t ws_size,
                              hipStream_t stream) {
    const float* x   = (const float*)d_in[0];
    const int*   ei  = (const int*)d_in[1];
    const float* W1l = (const float*)d_in[2];
    const float* b1  = (const float*)d_in[3];
    const float* W1r = (const float*)d_in[4];
    const float* W2l = (const float*)d_in[5];
    const float* b2  = (const float*)d_in[6];
    const float* W2r = (const float*)d_in[7];
    float* out = (float*)d_out;

    const int N_ = in_sizes[0] / IN_C;      // 50000
    const int E_ = in_sizes[1] / 2;         // 800000

    char* wsb = (char*)d_ws;
    size_t off = 0;
    auto alloc = [&](size_t bytes) {
        void* ptr = wsb + off;
        off += ((bytes + 15) & ~(size_t)15);
        return ptr;
    };
    unsigned short* Abf = (unsigned short*)alloc((size_t)N_ * 256 * 2);  // 25.6 MB
    unsigned int*   xh  = (unsigned int*)alloc((size_t)N_ * 64 * 4);     // 12.8 MB
    unsigned short* Bg  = (unsigned short*)alloc(256 * 256 * 2);         // 128 KB
    float* pr_part = (float*)alloc((size_t)N_ * 16 * 4);                 // 3.2 MB
    int*   deg    = (int*)alloc((size_t)N_ * 4);
    int*   rowptr = (int*)alloc((size_t)(N_ + 1) * 4);
    int*   cursor = (int*)alloc((size_t)N_ * 4);
    int*   elist  = (int*)alloc((size_t)E_ * 4);                         // 3.2 MB
    int*   bsum   = (int*)alloc(64 * 4);
    int*   boff   = (int*)alloc(64 * 4);
    float2* p2 = (float2*)alloc((size_t)N_ * 2 * 4);
    float2* rs = (float2*)alloc((size_t)N_ * 2 * 4);
    // total ~46 MB

    const int eb = (E_ + 255) / 256;
    const int nb = (N_ + SCAN_CHUNK - 1) / SCAN_CHUNK;   // 13

    // CSR build + conversions
    hipMemsetAsync(deg, 0, (size_t)N_ * sizeof(int), stream);
    hist_dst<<<eb, 256, 0, stream>>>(ei, deg, E_);
    convert_x<<<(N_ * 64 + 255) / 256, 256, 0, stream>>>(x, xh, (unsigned int*)Abf, N_ * 64);
    convert_w1<<<256, 256, 0, stream>>>(W1l, W1r, Bg);
    scan_p1<<<nb, 1024, 0, stream>>>(deg, rowptr, bsum, N_);
    scan_p2<<<1, 64, 0, stream>>>(bsum, boff, rowptr, nb, N_);
    scan_p3<<<nb, 1024, 0, stream>>>(rowptr, cursor, boff, N_);
    fill_csr<<<eb, 256, 0, stream>>>(ei, cursor, elist, E_);

    // Layer 1 GEMM with fused layer-2 projection
    gather_agg1<<<(N_ + 3) / 4, 256, 0, stream>>>(rowptr, elist, xh, (unsigned int*)Abf, N_);
    gemm1_fused<<<dim3((N_ + 127) / 128, 2), 256, 0, stream>>>(
        Abf, Bg, b1, W2l, W2r, pr_part, N_);

    // Layer 2 tail: combine partials, CSR gather, bias
    combine2<<<(N_ + 255) / 256, 256, 0, stream>>>(pr_part, p2, rs, N_);
    gather_fin<<<(N_ + 255) / 256, 256, 0, stream>>>(rowptr, elist, p2, rs, b2, out, N_);
}

// Round 7
// 236.276 us; speedup vs baseline: 17.9328x; 1.2367x over previous
//
#include <hip/hip_runtime.h>
#include <hip/hip_bf16.h>

// ---------------------------------------------------------------------------
// GraphSAGE 2-layer: h = relu(mean_agg(x) @ W1l^T + b1 + x @ W1r^T)
//                    out = mean_agg(h) @ W2l^T + b2 + h @ W2r^T
// N=50000, E=800000, C: 128 -> 256 -> 2.
// Round 7: replace hist_dst + scan + fill_csr (random 4B scatter -> 53 MB of
// partial-line HBM write-through) with a two-level counting sort:
//   bin_count -> bin_scan -> bin_scatter (block-claimed contiguous runs,
//   XCD-local lines) -> fine_sort (per-bucket LDS counting sort; emits
//   elist + rowptr coalesced). No per-node atomics anywhere.
// Rest unchanged: CSR gather agg (bf16), MFMA GEMM with fused layer-2
// projection epilogue (h never materialized), CSR gather finale.
// ---------------------------------------------------------------------------

#define IN_C 128
#define HID_C 256
#define BKT_SHIFT 7
#define BKT_W 128            // dsts per bucket
#define MAX_BKT_E 4096       // >= bucket edge count (mean 2046, sd ~45)

typedef __attribute__((ext_vector_type(8))) short short8;   // 8 bf16 (4 VGPRs)
typedef __attribute__((ext_vector_type(4))) float f32x4;    // MFMA accumulator

static __device__ __forceinline__ unsigned short f2b(float f) {
    __hip_bfloat16 h = __float2bfloat16(f);
    return *(unsigned short*)&h;
}
static __device__ __forceinline__ float b2f(unsigned short u) {
    unsigned v = ((unsigned)u) << 16;
    return *(float*)&v;
}

// ---- CSR build: two-level counting sort ------------------------------------

// Pass 1: coarse bucket histogram via LDS (no per-node atomics).
__global__ __launch_bounds__(256) void bin_count(const int* __restrict__ ei,
                                                 int* __restrict__ bhist, int E_) {
    __shared__ int hist[512];
    const int tid = threadIdx.x;
    for (int i = tid; i < 512; i += 256) hist[i] = 0;
    __syncthreads();
    const int e0 = blockIdx.x * 2048;
#pragma unroll
    for (int j = 0; j < 8; ++j) {
        int e = e0 + j * 256 + tid;
        if (e < E_) atomicAdd(&hist[ei[E_ + e] >> BKT_SHIFT], 1);
    }
    __syncthreads();
    for (int i = tid; i < 512; i += 256) {
        int c = hist[i];
        if (c) atomicAdd(&bhist[i], c);
    }
}

// Pass 2: scan bucket counts (one block, 512 threads).
__global__ __launch_bounds__(512) void bin_scan(const int* __restrict__ bhist,
                                                int* __restrict__ bbase,
                                                int* __restrict__ bcursor,
                                                int* __restrict__ rowptr,
                                                int nbkt, int n, int E_) {
    __shared__ int wsum[8];
    const int tid = threadIdx.x;
    const int lane = tid & 63;
    const int wid = tid >> 6;
    int v = (tid < nbkt) ? bhist[tid] : 0;
    int incl = v;
#pragma unroll
    for (int off = 1; off < 64; off <<= 1) {
        int t = __shfl_up(incl, off);
        if (lane >= off) incl += t;
    }
    if (lane == 63) wsum[wid] = incl;
    __syncthreads();
    int woff = 0;
    for (int w = 0; w < 8; ++w)
        if (w < wid) woff += wsum[w];
    int excl = woff + incl - v;
    if (tid < nbkt) { bbase[tid] = excl; bcursor[tid] = excl; }
    if (tid == 511) { bbase[nbkt] = woff + incl; rowptr[n] = E_; }
}

// Pass 3: scatter packed (src<<7 | dst_local) into per-block contiguous runs
// per bucket. Run lines are written by a single CU -> full-line writebacks.
__global__ __launch_bounds__(256) void bin_scatter(const int* __restrict__ ei,
                                                   int* __restrict__ bcursor,
                                                   unsigned int* __restrict__ binned,
                                                   int E_) {
    __shared__ int hist[512];
    __shared__ int lbase[512];
    const int tid = threadIdx.x;
    const int e0 = blockIdx.x * 4096;
    for (int i = tid; i < 512; i += 256) hist[i] = 0;
    __syncthreads();
#pragma unroll
    for (int j = 0; j < 16; ++j) {
        int e = e0 + j * 256 + tid;
        if (e < E_) atomicAdd(&hist[ei[E_ + e] >> BKT_SHIFT], 1);
    }
    __syncthreads();
    for (int i = tid; i < 512; i += 256) {
        int c = hist[i];
        lbase[i] = c ? atomicAdd(&bcursor[i], c) : 0;
        hist[i] = 0;   // reuse as local cursor
    }
    __syncthreads();
#pragma unroll
    for (int j = 0; j < 16; ++j) {
        int e = e0 + j * 256 + tid;
        if (e < E_) {
            int d = ei[E_ + e];
            int b = d >> BKT_SHIFT;
            int pos = lbase[b] + atomicAdd(&hist[b], 1);
            binned[pos] = ((unsigned)ei[e] << BKT_SHIFT) | (unsigned)(d & (BKT_W - 1));
        }
    }
}

// Pass 4: per-bucket LDS counting sort -> elist (src, dst-sorted) + rowptr.
__global__ __launch_bounds__(256) void fine_sort(const unsigned int* __restrict__ binned,
                                                 const int* __restrict__ bbase,
                                                 int* __restrict__ rowptr,
                                                 int* __restrict__ elist, int n) {
    __shared__ unsigned int ebuf[MAX_BKT_E];
    __shared__ unsigned short sbuf[MAX_BKT_E];
    __shared__ int hist[BKT_W];
    __shared__ int offs[BKT_W];
    __shared__ int cur[BKT_W];
    const int tid = threadIdx.x;
    const int lane = tid & 63;
    const int bkt = blockIdx.x;
    const int gbase = bbase[bkt];
    int cnt = bbase[bkt + 1] - gbase;
    if (cnt > MAX_BKT_E) cnt = MAX_BKT_E;   // defensive (P ~ 0)

    if (tid < BKT_W) hist[tid] = 0;
    for (int i = tid; i < cnt; i += 256) ebuf[i] = binned[gbase + i];
    __syncthreads();
    for (int i = tid; i < cnt; i += 256)
        atomicAdd(&hist[ebuf[i] & (BKT_W - 1)], 1);
    __syncthreads();
    if (tid < 64) {   // single-wave scan of 128 counts, 2/lane
        int h0 = hist[lane * 2], h1 = hist[lane * 2 + 1];
        int s = h0 + h1;
        int incl = s;
#pragma unroll
        for (int off = 1; off < 64; off <<= 1) {
            int t = __shfl_up(incl, off);
            if (lane >= off) incl += t;
        }
        int excl = incl - s;
        offs[lane * 2] = excl;         cur[lane * 2] = excl;
        offs[lane * 2 + 1] = excl + h0; cur[lane * 2 + 1] = excl + h0;
    }
    __syncthreads();
    // rowptr for this bucket's 128 dsts (coalesced)
    if (tid < BKT_W) {
        int d = bkt * BKT_W + tid;
        if (d < n) rowptr[d] = gbase + offs[tid];
    }
    // scatter into LDS by local dst
    for (int i = tid; i < cnt; i += 256) {
        unsigned int pk = ebuf[i];
        int pos = atomicAdd(&cur[pk & (BKT_W - 1)], 1);
        sbuf[pos] = (unsigned short)(pk >> BKT_SHIFT);
    }
    __syncthreads();
    // stream out (coalesced)
    for (int i = tid; i < cnt; i += 256)
        elist[gbase + i] = (int)sbuf[i];
}

// ---- bf16 conversions ------------------------------------------------------

// xh = bf16(x); also fill right half of A (cols 128..255).
__global__ void convert_x(const float* __restrict__ x, unsigned int* __restrict__ xh,
                          unsigned int* __restrict__ Abf, int npairs /* N*64 */) {
    int t = blockIdx.x * 256 + threadIdx.x;
    if (t >= npairs) return;
    float2 v = *(const float2*)&x[(size_t)t * 2];
    unsigned int o = ((unsigned)f2b(v.y) << 16) | f2b(v.x);
    xh[t] = o;
    int node = t >> 6, g = t & 63;
    Abf[(size_t)node * 128 + 64 + g] = o;   // A row = 256 bf16 = 128 uints
}

// Bg[o][k] = bf16(k<128 ? W1l[o][k] : W1r[o][k-128]); 256x256, k-contiguous.
__global__ void convert_w1(const float* __restrict__ w1l,
                           const float* __restrict__ w1r,
                           unsigned short* __restrict__ Bg) {
    int idx = blockIdx.x * 256 + threadIdx.x;   // 65536
    int o = idx >> 8, k = idx & 255;
    float f = (k < IN_C) ? w1l[o * IN_C + k] : w1r[o * IN_C + (k - IN_C)];
    Bg[idx] = f2b(f);
}

// ---- Layer-1 aggregation: one wave per node, bf16 gather, fp32 accumulate --

__global__ __launch_bounds__(256) void gather_agg1(
    const int* __restrict__ rowptr, const int* __restrict__ elist,
    const unsigned int* __restrict__ xh, unsigned int* __restrict__ Abf, int n) {
    int node = blockIdx.x * 4 + (threadIdx.x >> 6);
    int lane = threadIdx.x & 63;
    if (node >= n) return;
    int beg = rowptr[node], end = rowptr[node + 1];
    float sx = 0.0f, sy = 0.0f;
    int e = beg;
    for (; e + 1 < end; e += 2) {
        unsigned int u0 = xh[(size_t)elist[e] * 64 + lane];
        unsigned int u1 = xh[(size_t)elist[e + 1] * 64 + lane];
        sx += b2f(u0 & 0xffff) + b2f(u1 & 0xffff);
        sy += b2f(u0 >> 16) + b2f(u1 >> 16);
    }
    if (e < end) {
        unsigned int u0 = xh[(size_t)elist[e] * 64 + lane];
        sx += b2f(u0 & 0xffff);
        sy += b2f(u0 >> 16);
    }
    float inv = 1.0f / (float)max(end - beg, 1);
    unsigned int o = ((unsigned)f2b(sy * inv) << 16) | f2b(sx * inv);
    Abf[(size_t)node * 128 + lane] = o;   // left half of A row
}

// ---- Layer-1 GEMM + fused layer-2 projection -------------------------------

#define LSTR 72

__global__ __launch_bounds__(256) void gemm1_fused(
    const unsigned short* __restrict__ Abf, const unsigned short* __restrict__ Bg,
    const float* __restrict__ b1, const float* __restrict__ w2l,
    const float* __restrict__ w2r, float* __restrict__ pr_part, int nn) {
    __shared__ short As[128 * LSTR];
    __shared__ short Bs[128 * LSTR];

    const int tid = threadIdx.x;
    const int lane = tid & 63;
    const int wid = tid >> 6;
    const int wm = wid >> 1, wn = wid & 1;
    const int row0 = blockIdx.x * 128;
    const int col0 = blockIdx.y * 128;

    const int srow = tid >> 1;
    const int skc = (tid & 1) * 32;
    int arow = row0 + srow;
    if (arow >= nn) arow = nn - 1;
    const size_t agoff = (size_t)arow * 256 + skc;
    const size_t bgoff = (size_t)(col0 + srow) * 256 + skc;

    f32x4 acc[4][4];
#pragma unroll
    for (int i = 0; i < 4; ++i)
#pragma unroll
        for (int j = 0; j < 4; ++j) acc[i][j] = (f32x4){0.f, 0.f, 0.f, 0.f};

    const int quad = lane >> 4;     // 0..3
    const int l16 = lane & 15;

    for (int k0 = 0; k0 < 256; k0 += 64) {
        const uint4* ga = (const uint4*)(Abf + agoff + k0);
        const uint4* gb = (const uint4*)(Bg + bgoff + k0);
        uint4 va0 = ga[0], va1 = ga[1], va2 = ga[2], va3 = ga[3];
        uint4 vb0 = gb[0], vb1 = gb[1], vb2 = gb[2], vb3 = gb[3];

        __syncthreads();
        uint4* la = (uint4*)&As[srow * LSTR + skc];
        uint4* lb = (uint4*)&Bs[srow * LSTR + skc];
        la[0] = va0; la[1] = va1; la[2] = va2; la[3] = va3;
        lb[0] = vb0; lb[1] = vb1; lb[2] = vb2; lb[3] = vb3;
        __syncthreads();

#pragma unroll
        for (int kb = 0; kb < 2; ++kb) {
            short8 af[4], bf[4];
#pragma unroll
            for (int mt = 0; mt < 4; ++mt)
                af[mt] = *(const short8*)&As[(wm * 64 + mt * 16 + l16) * LSTR + kb * 32 + quad * 8];
#pragma unroll
            for (int nt = 0; nt < 4; ++nt)
                bf[nt] = *(const short8*)&Bs[(wn * 64 + nt * 16 + l16) * LSTR + kb * 32 + quad * 8];
#pragma unroll
            for (int mt = 0; mt < 4; ++mt)
#pragma unroll
                for (int nt = 0; nt < 4; ++nt)
                    acc[mt][nt] = __builtin_amdgcn_mfma_f32_16x16x32_bf16(
                        af[mt], bf[nt], acc[mt][nt], 0, 0, 0);
        }
    }

    // ---- fused projection epilogue (no h materialization) ----
    const int cbase = col0 + wn * 64 + l16;
    const int cby = blockIdx.y * 2 + wn;   // 0..3 column slot
#pragma unroll
    for (int half = 0; half < 2; ++half) {
        const float* wA = half ? w2r : w2l;          // rows 0,1 of W2{l,r}
        f32x4 part[2][4];
#pragma unroll
        for (int c = 0; c < 2; ++c)
#pragma unroll
            for (int mt = 0; mt < 4; ++mt) part[c][mt] = (f32x4){0.f, 0.f, 0.f, 0.f};
#pragma unroll
        for (int nt = 0; nt < 4; ++nt) {
            const int col = cbase + nt * 16;
            const float bias = b1[col];
            const float w0 = wA[col];
            const float w1 = wA[HID_C + col];
#pragma unroll
            for (int mt = 0; mt < 4; ++mt)
#pragma unroll
                for (int r = 0; r < 4; ++r) {
                    float hv = fmaxf(acc[mt][nt][r] + bias, 0.0f);
                    part[0][mt][r] += hv * w0;
                    part[1][mt][r] += hv * w1;
                }
        }
#pragma unroll
        for (int c = 0; c < 2; ++c)
#pragma unroll
            for (int mt = 0; mt < 4; ++mt)
#pragma unroll
                for (int r = 0; r < 4; ++r)
#pragma unroll
                    for (int m = 1; m < 16; m <<= 1)
                        part[c][mt][r] += __shfl_xor(part[c][mt][r], m);
        if (l16 < 8) {
            const int ch2 = l16 & 1;
            const int mts = l16 >> 1;
#pragma unroll
            for (int r = 0; r < 4; ++r) {
                int row = row0 + wm * 64 + quad * 4 + mts * 16 + r;
                if (row < nn)
                    pr_part[(size_t)row * 16 + cby * 4 + half * 2 + ch2] =
                        part[ch2][mts][r];
            }
        }
    }
}

// ---- Layer 2 tail ----------------------------------------------------------

__global__ void combine2(const float* __restrict__ pr_part,
                         float2* __restrict__ p2, float2* __restrict__ rs, int n) {
    int i = blockIdx.x * 256 + threadIdx.x;
    if (i >= n) return;
    const float4* q = (const float4*)(pr_part + (size_t)i * 16);
    float4 a = q[0], b = q[1], c = q[2], d = q[3];
    p2[i] = make_float2(a.x + b.x + c.x + d.x, a.y + b.y + c.y + d.y);
    rs[i] = make_float2(a.z + b.z + c.z + d.z, a.w + b.w + c.w + d.w);
}

__global__ void gather_fin(const int* __restrict__ rowptr, const int* __restrict__ elist,
                           const float2* __restrict__ p2, const float2* __restrict__ rs,
                           const float* __restrict__ b2, float* __restrict__ out, int n) {
    int i = blockIdx.x * 256 + threadIdx.x;
    if (i >= n) return;
    int beg = rowptr[i], end = rowptr[i + 1];
    float s0 = 0.0f, s1 = 0.0f;
    for (int e = beg; e < end; ++e) {
        float2 v = p2[elist[e]];
        s0 += v.x; s1 += v.y;
    }
    float inv = 1.0f / (float)max(end - beg, 1);
    float2 self = rs[i];
    out[i * 2 + 0] = s0 * inv + self.x + b2[0];
    out[i * 2 + 1] = s1 * inv + self.y + b2[1];
}

// ---- launch ----------------------------------------------------------------

extern "C" void kernel_launch(void* const* d_in, const int* in_sizes, int n_in,
                              void* d_out, int out_size, void* d_ws, size_t ws_size,
                              hipStream_t stream) {
    const float* x   = (const float*)d_in[0];
    const int*   ei  = (const int*)d_in[1];
    const float* W1l = (const float*)d_in[2];
    const float* b1  = (const float*)d_in[3];
    const float* W1r = (const float*)d_in[4];
    const float* W2l = (const float*)d_in[5];
    const float* b2  = (const float*)d_in[6];
    const float* W2r = (const float*)d_in[7];
    float* out = (float*)d_out;

    const int N_ = in_sizes[0] / IN_C;      // 50000
    const int E_ = in_sizes[1] / 2;         // 800000
    const int nbkt = (N_ + BKT_W - 1) / BKT_W;   // 391

    char* wsb = (char*)d_ws;
    size_t off = 0;
    auto alloc = [&](size_t bytes) {
        void* ptr = wsb + off;
        off += ((bytes + 15) & ~(size_t)15);
        return ptr;
    };
    unsigned short* Abf = (unsigned short*)alloc((size_t)N_ * 256 * 2);  // 25.6 MB
    unsigned int*   xh  = (unsigned int*)alloc((size_t)N_ * 64 * 4);     // 12.8 MB
    unsigned short* Bg  = (unsigned short*)alloc(256 * 256 * 2);         // 128 KB
    float* pr_part = (float*)alloc((size_t)N_ * 16 * 4);                 // 3.2 MB
    int*   rowptr = (int*)alloc((size_t)(N_ + 1) * 4);
    int*   elist  = (int*)alloc((size_t)E_ * 4);                         // 3.2 MB
    unsigned int* binned = (unsigned int*)alloc((size_t)E_ * 4);         // 3.2 MB
    int*   bhist  = (int*)alloc(512 * 4);
    int*   bbase  = (int*)alloc(513 * 4);
    int*   bcursor= (int*)alloc(512 * 4);
    float2* p2 = (float2*)alloc((size_t)N_ * 2 * 4);
    float2* rs = (float2*)alloc((size_t)N_ * 2 * 4);
    // total ~50 MB

    // CSR build: two-level counting sort (+ independent conversions)
    hipMemsetAsync(bhist, 0, 512 * sizeof(int), stream);
    bin_count<<<(E_ + 2047) / 2048, 256, 0, stream>>>(ei, bhist, E_);
    convert_x<<<(N_ * 64 + 255) / 256, 256, 0, stream>>>(x, xh, (unsigned int*)Abf, N_ * 64);
    convert_w1<<<256, 256, 0, stream>>>(W1l, W1r, Bg);
    bin_scan<<<1, 512, 0, stream>>>(bhist, bbase, bcursor, rowptr, nbkt, N_, E_);
    bin_scatter<<<(E_ + 4095) / 4096, 256, 0, stream>>>(ei, bcursor, binned, E_);
    fine_sort<<<nbkt, 256, 0, stream>>>(binned, bbase, rowptr, elist, N_);

    // Layer 1 GEMM with fused layer-2 projection
    gather_agg1<<<(N_ + 3) / 4, 256, 0, stream>>>(rowptr, elist, xh, (unsigned int*)Abf, N_);
    gemm1_fused<<<dim3((N_ + 127) / 128, 2), 256, 0, stream>>>(
        Abf, Bg, b1, W2l, W2r, pr_part, N_);

    // Layer 2 tail: combine partials, CSR gather, bias
    combine2<<<(N_ + 255) / 256, 256, 0, stream>>>(pr_part, p2, rs, N_);
    gather_fin<<<(N_ + 255) / 256, 256, 0, stream>>>(rowptr, elist, p2, rs, b2, out, N_);
}

// Round 8
// 219.320 us; speedup vs baseline: 19.3192x; 1.0773x over previous
//
#include <hip/hip_runtime.h>
#include <hip/hip_bf16.h>

// ---------------------------------------------------------------------------
// GraphSAGE 2-layer: h = relu(mean_agg(x) @ W1l^T + b1 + x @ W1r^T)
//                    out = mean_agg(h) @ W2l^T + b2 + h @ W2r^T
// N=50000, E=800000, C: 128 -> 256 -> 2.
// Round 8: gather_agg1 was L3-latency-bound (51 us, VALUBusy 29%) -- one node
// per wave, 4B/lane loads, 2 edges in flight. New layout: lane = (ep, pos),
// uint4 loads -> 4 edges per instruction, x2 unroll = 8 edges/iter, cross-edge
// shfl_xor reduce. convert_w1 folded into convert_x. Rest unchanged.
// ---------------------------------------------------------------------------

#define IN_C 128
#define HID_C 256
#define BKT_SHIFT 7
#define BKT_W 128            // dsts per bucket
#define MAX_BKT_E 4096       // >= bucket edge count (mean 2046, sd ~45)

typedef __attribute__((ext_vector_type(8))) short short8;   // 8 bf16 (4 VGPRs)
typedef __attribute__((ext_vector_type(4))) float f32x4;    // MFMA accumulator

static __device__ __forceinline__ unsigned short f2b(float f) {
    __hip_bfloat16 h = __float2bfloat16(f);
    return *(unsigned short*)&h;
}
static __device__ __forceinline__ float b2f(unsigned short u) {
    unsigned v = ((unsigned)u) << 16;
    return *(float*)&v;
}

// ---- CSR build: two-level counting sort ------------------------------------

__global__ __launch_bounds__(256) void bin_count(const int* __restrict__ ei,
                                                 int* __restrict__ bhist, int E_) {
    __shared__ int hist[512];
    const int tid = threadIdx.x;
    for (int i = tid; i < 512; i += 256) hist[i] = 0;
    __syncthreads();
    const int e0 = blockIdx.x * 2048;
#pragma unroll
    for (int j = 0; j < 8; ++j) {
        int e = e0 + j * 256 + tid;
        if (e < E_) atomicAdd(&hist[ei[E_ + e] >> BKT_SHIFT], 1);
    }
    __syncthreads();
    for (int i = tid; i < 512; i += 256) {
        int c = hist[i];
        if (c) atomicAdd(&bhist[i], c);
    }
}

__global__ __launch_bounds__(512) void bin_scan(const int* __restrict__ bhist,
                                                int* __restrict__ bbase,
                                                int* __restrict__ bcursor,
                                                int* __restrict__ rowptr,
                                                int nbkt, int n, int E_) {
    __shared__ int wsum[8];
    const int tid = threadIdx.x;
    const int lane = tid & 63;
    const int wid = tid >> 6;
    int v = (tid < nbkt) ? bhist[tid] : 0;
    int incl = v;
#pragma unroll
    for (int off = 1; off < 64; off <<= 1) {
        int t = __shfl_up(incl, off);
        if (lane >= off) incl += t;
    }
    if (lane == 63) wsum[wid] = incl;
    __syncthreads();
    int woff = 0;
    for (int w = 0; w < 8; ++w)
        if (w < wid) woff += wsum[w];
    int excl = woff + incl - v;
    if (tid < nbkt) { bbase[tid] = excl; bcursor[tid] = excl; }
    if (tid == 511) { bbase[nbkt] = woff + incl; rowptr[n] = E_; }
}

__global__ __launch_bounds__(256) void bin_scatter(const int* __restrict__ ei,
                                                   int* __restrict__ bcursor,
                                                   unsigned int* __restrict__ binned,
                                                   int E_) {
    __shared__ int hist[512];
    __shared__ int lbase[512];
    const int tid = threadIdx.x;
    const int e0 = blockIdx.x * 4096;
    for (int i = tid; i < 512; i += 256) hist[i] = 0;
    __syncthreads();
#pragma unroll
    for (int j = 0; j < 16; ++j) {
        int e = e0 + j * 256 + tid;
        if (e < E_) atomicAdd(&hist[ei[E_ + e] >> BKT_SHIFT], 1);
    }
    __syncthreads();
    for (int i = tid; i < 512; i += 256) {
        int c = hist[i];
        lbase[i] = c ? atomicAdd(&bcursor[i], c) : 0;
        hist[i] = 0;   // reuse as local cursor
    }
    __syncthreads();
#pragma unroll
    for (int j = 0; j < 16; ++j) {
        int e = e0 + j * 256 + tid;
        if (e < E_) {
            int d = ei[E_ + e];
            int b = d >> BKT_SHIFT;
            int pos = lbase[b] + atomicAdd(&hist[b], 1);
            binned[pos] = ((unsigned)ei[e] << BKT_SHIFT) | (unsigned)(d & (BKT_W - 1));
        }
    }
}

__global__ __launch_bounds__(256) void fine_sort(const unsigned int* __restrict__ binned,
                                                 const int* __restrict__ bbase,
                                                 int* __restrict__ rowptr,
                                                 int* __restrict__ elist, int n) {
    __shared__ unsigned int ebuf[MAX_BKT_E];
    __shared__ unsigned short sbuf[MAX_BKT_E];
    __shared__ int hist[BKT_W];
    __shared__ int offs[BKT_W];
    __shared__ int cur[BKT_W];
    const int tid = threadIdx.x;
    const int lane = tid & 63;
    const int bkt = blockIdx.x;
    const int gbase = bbase[bkt];
    int cnt = bbase[bkt + 1] - gbase;
    if (cnt > MAX_BKT_E) cnt = MAX_BKT_E;   // defensive (P ~ 0)

    if (tid < BKT_W) hist[tid] = 0;
    for (int i = tid; i < cnt; i += 256) ebuf[i] = binned[gbase + i];
    __syncthreads();
    for (int i = tid; i < cnt; i += 256)
        atomicAdd(&hist[ebuf[i] & (BKT_W - 1)], 1);
    __syncthreads();
    if (tid < 64) {   // single-wave scan of 128 counts, 2/lane
        int h0 = hist[lane * 2], h1 = hist[lane * 2 + 1];
        int s = h0 + h1;
        int incl = s;
#pragma unroll
        for (int off = 1; off < 64; off <<= 1) {
            int t = __shfl_up(incl, off);
            if (lane >= off) incl += t;
        }
        int excl = incl - s;
        offs[lane * 2] = excl;         cur[lane * 2] = excl;
        offs[lane * 2 + 1] = excl + h0; cur[lane * 2 + 1] = excl + h0;
    }
    __syncthreads();
    if (tid < BKT_W) {
        int d = bkt * BKT_W + tid;
        if (d < n) rowptr[d] = gbase + offs[tid];
    }
    for (int i = tid; i < cnt; i += 256) {
        unsigned int pk = ebuf[i];
        int pos = atomicAdd(&cur[pk & (BKT_W - 1)], 1);
        sbuf[pos] = (unsigned short)(pk >> BKT_SHIFT);
    }
    __syncthreads();
    for (int i = tid; i < cnt; i += 256)
        elist[gbase + i] = (int)sbuf[i];
}

// ---- bf16 conversions (x and W1 fused in one dispatch) ---------------------

// Blocks [0, xblk): xh = bf16(x), fill right half of A.
// Blocks [xblk, xblk+256): Bg[o][k] = bf16([W1l | W1r]).
__global__ void convert_all(const float* __restrict__ x, unsigned int* __restrict__ xh,
                            unsigned int* __restrict__ Abf,
                            const float* __restrict__ w1l, const float* __restrict__ w1r,
                            unsigned short* __restrict__ Bg,
                            int npairs /* N*64 */, int xblk) {
    if (blockIdx.x < xblk) {
        int t = blockIdx.x * 256 + threadIdx.x;
        if (t >= npairs) return;
        float2 v = *(const float2*)&x[(size_t)t * 2];
        unsigned int o = ((unsigned)f2b(v.y) << 16) | f2b(v.x);
        xh[t] = o;
        int node = t >> 6, g = t & 63;
        Abf[(size_t)node * 128 + 64 + g] = o;   // A row = 256 bf16 = 128 uints
    } else {
        int idx = (blockIdx.x - xblk) * 256 + threadIdx.x;   // 65536
        int o = idx >> 8, k = idx & 255;
        float f = (k < IN_C) ? w1l[o * IN_C + k] : w1r[o * IN_C + (k - IN_C)];
        Bg[idx] = f2b(f);
    }
}

// ---- Layer-1 aggregation: 4 edges per load instruction ---------------------
// Wave layout: ep = lane>>4 (edge slot 0..3), pos = lane&15 (uint4 = 8 feats).
// One uint4 load fetches 4 full 256B source rows, coalesced. x2 unroll = 8
// edges in flight per iteration; cross-edge reduce via shfl_xor(16,32).

__global__ __launch_bounds__(256) void gather_agg1(
    const int* __restrict__ rowptr, const int* __restrict__ elist,
    const uint4* __restrict__ xh4, uint4* __restrict__ Abf4, int n) {
    int node = blockIdx.x * 4 + (threadIdx.x >> 6);
    int lane = threadIdx.x & 63;
    if (node >= n) return;
    const int ep = lane >> 4;
    const int pos = lane & 15;
    int beg = rowptr[node], end = rowptr[node + 1];

    float s[8] = {0.f, 0.f, 0.f, 0.f, 0.f, 0.f, 0.f, 0.f};
    for (int e = beg; e < end; e += 8) {
        int e0 = e + ep;
        int e1 = e + 4 + ep;
        if (e0 < end) {
            uint4 u = xh4[(size_t)elist[e0] * 16 + pos];
            s[0] += b2f(u.x & 0xffff); s[1] += b2f(u.x >> 16);
            s[2] += b2f(u.y & 0xffff); s[3] += b2f(u.y >> 16);
            s[4] += b2f(u.z & 0xffff); s[5] += b2f(u.z >> 16);
            s[6] += b2f(u.w & 0xffff); s[7] += b2f(u.w >> 16);
        }
        if (e1 < end) {
            uint4 u = xh4[(size_t)elist[e1] * 16 + pos];
            s[0] += b2f(u.x & 0xffff); s[1] += b2f(u.x >> 16);
            s[2] += b2f(u.y & 0xffff); s[3] += b2f(u.y >> 16);
            s[4] += b2f(u.z & 0xffff); s[5] += b2f(u.z >> 16);
            s[6] += b2f(u.w & 0xffff); s[7] += b2f(u.w >> 16);
        }
    }
    // reduce the 4 edge slots (lanes 16 apart hold same features)
#pragma unroll
    for (int i = 0; i < 8; ++i) {
        s[i] += __shfl_xor(s[i], 16);
        s[i] += __shfl_xor(s[i], 32);
    }
    if (ep == 0) {
        float inv = 1.0f / (float)max(end - beg, 1);
        uint4 o;
        o.x = ((unsigned)f2b(s[1] * inv) << 16) | f2b(s[0] * inv);
        o.y = ((unsigned)f2b(s[3] * inv) << 16) | f2b(s[2] * inv);
        o.z = ((unsigned)f2b(s[5] * inv) << 16) | f2b(s[4] * inv);
        o.w = ((unsigned)f2b(s[7] * inv) << 16) | f2b(s[6] * inv);
        Abf4[(size_t)node * 32 + pos] = o;   // left half of A row (16 uint4)
    }
}

// ---- Layer-1 GEMM + fused layer-2 projection -------------------------------

#define LSTR 72

__global__ __launch_bounds__(256) void gemm1_fused(
    const unsigned short* __restrict__ Abf, const unsigned short* __restrict__ Bg,
    const float* __restrict__ b1, const float* __restrict__ w2l,
    const float* __restrict__ w2r, float* __restrict__ pr_part, int nn) {
    __shared__ short As[128 * LSTR];
    __shared__ short Bs[128 * LSTR];

    const int tid = threadIdx.x;
    const int lane = tid & 63;
    const int wid = tid >> 6;
    const int wm = wid >> 1, wn = wid & 1;
    const int row0 = blockIdx.x * 128;
    const int col0 = blockIdx.y * 128;

    const int srow = tid >> 1;
    const int skc = (tid & 1) * 32;
    int arow = row0 + srow;
    if (arow >= nn) arow = nn - 1;
    const size_t agoff = (size_t)arow * 256 + skc;
    const size_t bgoff = (size_t)(col0 + srow) * 256 + skc;

    f32x4 acc[4][4];
#pragma unroll
    for (int i = 0; i < 4; ++i)
#pragma unroll
        for (int j = 0; j < 4; ++j) acc[i][j] = (f32x4){0.f, 0.f, 0.f, 0.f};

    const int quad = lane >> 4;     // 0..3
    const int l16 = lane & 15;

    for (int k0 = 0; k0 < 256; k0 += 64) {
        const uint4* ga = (const uint4*)(Abf + agoff + k0);
        const uint4* gb = (const uint4*)(Bg + bgoff + k0);
        uint4 va0 = ga[0], va1 = ga[1], va2 = ga[2], va3 = ga[3];
        uint4 vb0 = gb[0], vb1 = gb[1], vb2 = gb[2], vb3 = gb[3];

        __syncthreads();
        uint4* la = (uint4*)&As[srow * LSTR + skc];
        uint4* lb = (uint4*)&Bs[srow * LSTR + skc];
        la[0] = va0; la[1] = va1; la[2] = va2; la[3] = va3;
        lb[0] = vb0; lb[1] = vb1; lb[2] = vb2; lb[3] = vb3;
        __syncthreads();

#pragma unroll
        for (int kb = 0; kb < 2; ++kb) {
            short8 af[4], bf[4];
#pragma unroll
            for (int mt = 0; mt < 4; ++mt)
                af[mt] = *(const short8*)&As[(wm * 64 + mt * 16 + l16) * LSTR + kb * 32 + quad * 8];
#pragma unroll
            for (int nt = 0; nt < 4; ++nt)
                bf[nt] = *(const short8*)&Bs[(wn * 64 + nt * 16 + l16) * LSTR + kb * 32 + quad * 8];
#pragma unroll
            for (int mt = 0; mt < 4; ++mt)
#pragma unroll
                for (int nt = 0; nt < 4; ++nt)
                    acc[mt][nt] = __builtin_amdgcn_mfma_f32_16x16x32_bf16(
                        af[mt], bf[nt], acc[mt][nt], 0, 0, 0);
        }
    }

    // ---- fused projection epilogue (no h materialization) ----
    const int cbase = col0 + wn * 64 + l16;
    const int cby = blockIdx.y * 2 + wn;   // 0..3 column slot
#pragma unroll
    for (int half = 0; half < 2; ++half) {
        const float* wA = half ? w2r : w2l;          // rows 0,1 of W2{l,r}
        f32x4 part[2][4];
#pragma unroll
        for (int c = 0; c < 2; ++c)
#pragma unroll
            for (int mt = 0; mt < 4; ++mt) part[c][mt] = (f32x4){0.f, 0.f, 0.f, 0.f};
#pragma unroll
        for (int nt = 0; nt < 4; ++nt) {
            const int col = cbase + nt * 16;
            const float bias = b1[col];
            const float w0 = wA[col];
            const float w1 = wA[HID_C + col];
#pragma unroll
            for (int mt = 0; mt < 4; ++mt)
#pragma unroll
                for (int r = 0; r < 4; ++r) {
                    float hv = fmaxf(acc[mt][nt][r] + bias, 0.0f);
                    part[0][mt][r] += hv * w0;
                    part[1][mt][r] += hv * w1;
                }
        }
#pragma unroll
        for (int c = 0; c < 2; ++c)
#pragma unroll
            for (int mt = 0; mt < 4; ++mt)
#pragma unroll
                for (int r = 0; r < 4; ++r)
#pragma unroll
                    for (int m = 1; m < 16; m <<= 1)
                        part[c][mt][r] += __shfl_xor(part[c][mt][r], m);
        if (l16 < 8) {
            const int ch2 = l16 & 1;
            const int mts = l16 >> 1;
#pragma unroll
            for (int r = 0; r < 4; ++r) {
                int row = row0 + wm * 64 + quad * 4 + mts * 16 + r;
                if (row < nn)
                    pr_part[(size_t)row * 16 + cby * 4 + half * 2 + ch2] =
                        part[ch2][mts][r];
            }
        }
    }
}

// ---- Layer 2 tail ----------------------------------------------------------

__global__ void combine2(const float* __restrict__ pr_part,
                         float2* __restrict__ p2, float2* __restrict__ rs, int n) {
    int i = blockIdx.x * 256 + threadIdx.x;
    if (i >= n) return;
    const float4* q = (const float4*)(pr_part + (size_t)i * 16);
    float4 a = q[0], b = q[1], c = q[2], d = q[3];
    p2[i] = make_float2(a.x + b.x + c.x + d.x, a.y + b.y + c.y + d.y);
    rs[i] = make_float2(a.z + b.z + c.z + d.z, a.w + b.w + c.w + d.w);
}

__global__ void gather_fin(const int* __restrict__ rowptr, const int* __restrict__ elist,
                           const float2* __restrict__ p2, const float2* __restrict__ rs,
                           const float* __restrict__ b2, float* __restrict__ out, int n) {
    int i = blockIdx.x * 256 + threadIdx.x;
    if (i >= n) return;
    int beg = rowptr[i], end = rowptr[i + 1];
    float s0 = 0.0f, s1 = 0.0f;
    for (int e = beg; e < end; ++e) {
        float2 v = p2[elist[e]];
        s0 += v.x; s1 += v.y;
    }
    float inv = 1.0f / (float)max(end - beg, 1);
    float2 self = rs[i];
    out[i * 2 + 0] = s0 * inv + self.x + b2[0];
    out[i * 2 + 1] = s1 * inv + self.y + b2[1];
}

// ---- launch ----------------------------------------------------------------

extern "C" void kernel_launch(void* const* d_in, const int* in_sizes, int n_in,
                              void* d_out, int out_size, void* d_ws, size_t ws_size,
                              hipStream_t stream) {
    const float* x   = (const float*)d_in[0];
    const int*   ei  = (const int*)d_in[1];
    const float* W1l = (const float*)d_in[2];
    const float* b1  = (const float*)d_in[3];
    const float* W1r = (const float*)d_in[4];
    const float* W2l = (const float*)d_in[5];
    const float* b2  = (const float*)d_in[6];
    const float* W2r = (const float*)d_in[7];
    float* out = (float*)d_out;

    const int N_ = in_sizes[0] / IN_C;      // 50000
    const int E_ = in_sizes[1] / 2;         // 800000
    const int nbkt = (N_ + BKT_W - 1) / BKT_W;   // 391

    char* wsb = (char*)d_ws;
    size_t off = 0;
    auto alloc = [&](size_t bytes) {
        void* ptr = wsb + off;
        off += ((bytes + 15) & ~(size_t)15);
        return ptr;
    };
    unsigned short* Abf = (unsigned short*)alloc((size_t)N_ * 256 * 2);  // 25.6 MB
    unsigned int*   xh  = (unsigned int*)alloc((size_t)N_ * 64 * 4);     // 12.8 MB
    unsigned short* Bg  = (unsigned short*)alloc(256 * 256 * 2);         // 128 KB
    float* pr_part = (float*)alloc((size_t)N_ * 16 * 4);                 // 3.2 MB
    int*   rowptr = (int*)alloc((size_t)(N_ + 1) * 4);
    int*   elist  = (int*)alloc((size_t)E_ * 4);                         // 3.2 MB
    unsigned int* binned = (unsigned int*)alloc((size_t)E_ * 4);         // 3.2 MB
    int*   bhist  = (int*)alloc(512 * 4);
    int*   bbase  = (int*)alloc(513 * 4);
    int*   bcursor= (int*)alloc(512 * 4);
    float2* p2 = (float2*)alloc((size_t)N_ * 2 * 4);
    float2* rs = (float2*)alloc((size_t)N_ * 2 * 4);
    // total ~50 MB

    const int xblk = (N_ * 64 + 255) / 256;

    // CSR build: two-level counting sort (+ independent conversions)
    hipMemsetAsync(bhist, 0, 512 * sizeof(int), stream);
    bin_count<<<(E_ + 2047) / 2048, 256, 0, stream>>>(ei, bhist, E_);
    convert_all<<<xblk + 256, 256, 0, stream>>>(x, xh, (unsigned int*)Abf,
                                                W1l, W1r, Bg, N_ * 64, xblk);
    bin_scan<<<1, 512, 0, stream>>>(bhist, bbase, bcursor, rowptr, nbkt, N_, E_);
    bin_scatter<<<(E_ + 4095) / 4096, 256, 0, stream>>>(ei, bcursor, binned, E_);
    fine_sort<<<nbkt, 256, 0, stream>>>(binned, bbase, rowptr, elist, N_);

    // Layer 1 GEMM with fused layer-2 projection
    gather_agg1<<<(N_ + 3) / 4, 256, 0, stream>>>(rowptr, elist,
                                                  (const uint4*)xh, (uint4*)Abf, N_);
    gemm1_fused<<<dim3((N_ + 127) / 128, 2), 256, 0, stream>>>(
        Abf, Bg, b1, W2l, W2r, pr_part, N_);

    // Layer 2 tail: combine partials, CSR gather, bias
    combine2<<<(N_ + 255) / 256, 256, 0, stream>>>(pr_part, p2, rs, N_);
    gather_fin<<<(N_ + 255) / 256, 256, 0, stream>>>(rowptr, elist, p2, rs, b2, out, N_);
}